// Round 2
// baseline (2204.773 us; speedup 1.0000x reference)
//
#include <hip/hip_runtime.h>
#include <math.h>

#define PI_D 3.14159265358979323846

// ---------------- dims ----------------
#define BATCH   1024
#define TLEN    16000
#define NFFT    400
#define HOP     200
#define NFRAME  81          // 1 + (16400-400)/200
#define NBIN    201
#define NMEL    128
#define HID     128
#define TSTEPS  79          // after conv k=3 valid
#define GATES   512         // 4*HID

// DFT table layout: [400][448]; cos at cols 0..200, sin at cols 224..424, rest 0
#define TLD     448
#define FBROWS  208         // 201 padded to BK multiple

#define NCHUNK  8
#define CHROWS  (BATCH*NFRAME/NCHUNK)   // 10368

// ---------------- workspace layout ----------------
static inline size_t al512(size_t v){ return (v + 511) & ~((size_t)511); }

// ---------------- setup kernels (double precision) ----------------
__global__ void setup_dft(float* __restrict__ T){
    int idx = blockIdx.x*256 + threadIdx.x;
    if (idx >= NFFT*TLD) return;
    int n = idx / TLD, c = idx % TLD;
    double w = 0.5 - 0.5*cos(2.0*PI_D*(double)n/400.0);   // periodic hann(400)
    double v = 0.0;
    if (c < NBIN) {
        v = w * cos(2.0*PI_D*(double)((n*c)%400)/400.0);
    } else if (c >= 224 && c < 224+NBIN) {
        int k = c - 224;
        v = w * sin(2.0*PI_D*(double)((n*k)%400)/400.0);  // sign irrelevant (squared)
    }
    T[idx] = (float)v;
}

__global__ void setup_fb(float* __restrict__ fb){
    int idx = blockIdx.x*256 + threadIdx.x;
    if (idx >= FBROWS*NMEL) return;
    int f = idx / NMEL, m = idx % NMEL;
    float v = 0.f;
    if (f < NBIN) {
        double melmax = 2595.0 * log10(1.0 + 8000.0/700.0);
        double p0 = 700.0*(pow(10.0, melmax*(double)(m  )/129.0/2595.0) - 1.0);
        double p1 = 700.0*(pow(10.0, melmax*(double)(m+1)/129.0/2595.0) - 1.0);
        double p2 = 700.0*(pow(10.0, melmax*(double)(m+2)/129.0/2595.0) - 1.0);
        double freq = 40.0 * (double)f;   // 8000/200 * f
        double dn = (freq - p0)/(p1 - p0);
        double up = (p2 - freq)/(p2 - p1);
        double t  = dn < up ? dn : up;
        if (t < 0.0) t = 0.0;
        v = (float)t;
    }
    fb[idx] = v;
}

__global__ void setup_wc(float* __restrict__ wc, const float* __restrict__ cw){
    int idx = blockIdx.x*256 + threadIdx.x;
    if (idx >= 384*128) return;
    int kk = idx / 128, o = idx % 128;
    int ksh = kk >> 7, i = kk & 127;
    wc[idx] = cw[o*384 + i*3 + ksh];
}

__global__ void setup_comb(float* __restrict__ cwm, float* __restrict__ cb,
                           const float* __restrict__ fc1w, const float* __restrict__ fc1b,
                           const float* __restrict__ projw, const float* __restrict__ projb){
    int idx = blockIdx.x*256 + threadIdx.x;
    if (idx < 128*64) {
        int i = idx / 64, o = idx % 64;
        float v = 0.f;
        if (o < 35) {
            double s = 0.0;
            for (int m = 0; m < 128; m++) s += (double)fc1w[i*128+m] * (double)projw[m*35+o];
            v = (float)s;
        }
        cwm[idx] = v;
    } else if (idx < 128*64 + 64) {
        int o = idx - 128*64;
        float v = 0.f;
        if (o < 35) {
            double s = (double)projb[o];
            for (int m = 0; m < 128; m++) s += (double)fc1b[m] * (double)projw[m*35+o];
            v = (float)s;
        }
        cb[o] = v;
    }
}

// ---------------- generic tiled GEMM ----------------
#define BM 64
#define BN 64
#define BK 16

enum AMode { A_NORMAL=0, A_FRAMES=1, A_POWER=2, A_CONV3=3 };

template<int AMODE, bool BIAS>
__global__ __launch_bounds__(256)
void gemm_k(const float* __restrict__ A, const float* __restrict__ Bm,
            const float* __restrict__ bias, float* __restrict__ C,
            int M, int N, int K, int lda, int ldb, int ldc,
            const float* __restrict__ aux, int rowbase)
{
    __shared__ float As[BK][BM+4];
    __shared__ float Bs[BK][BN];
    const int tid = threadIdx.x;
    const int tx = tid & 15, ty = tid >> 4;
    const int m0 = blockIdx.x * BM;
    const int n0 = blockIdx.y * BN;

    float acc[4][4] = {{0,0,0,0},{0,0,0,0},{0,0,0,0},{0,0,0,0}};

    const int am = tid >> 2;          // tile row 0..63
    const int ak = (tid & 3) * 4;     // k segment
    const int bk = tid >> 4;          // 0..15
    const int bn = (tid & 15) * 4;

    for (int k0 = 0; k0 < K; k0 += BK) {
        // ---- A tile ----
        float4 av = make_float4(0.f,0.f,0.f,0.f);
        {
            const int row = m0 + am;
            const int kk  = k0 + ak;
            if constexpr (AMODE == A_NORMAL) {
                if (row < M) av = *(const float4*)(A + (size_t)row*lda + kk);
            } else if constexpr (AMODE == A_POWER) {
                if (row < M) {
                    float4 re = *(const float4*)(A + (size_t)row*lda + kk);
                    float4 im = *(const float4*)(A + (size_t)row*lda + 224 + kk);
                    av.x = re.x*re.x + im.x*im.x;
                    av.y = re.y*re.y + im.y*im.y;
                    av.z = re.z*re.z + im.z*im.z;
                    av.w = re.w*re.w + im.w*im.w;
                }
            } else if constexpr (AMODE == A_FRAMES) {
                if (row < M) {
                    const int r = rowbase + row;
                    const int b = r / NFRAME, f = r - b*NFRAME;
                    const float* xb = aux + (size_t)b * TLEN;
                    float tmp[4];
                    #pragma unroll
                    for (int j = 0; j < 4; j++) {
                        int q = f*HOP + (kk + j) - 200;
                        if (q < 0) q = -q;
                        else if (q >= TLEN) q = 2*TLEN - 2 - q;
                        tmp[j] = xb[q];
                    }
                    av = make_float4(tmp[0], tmp[1], tmp[2], tmp[3]);
                }
            } else { // A_CONV3
                if (row < M) {
                    const int r = row;
                    const int b = r / TSTEPS, t = r - b*TSTEPS;
                    const int ksh = kk >> 7, i = kk & 127;
                    av = *(const float4*)(aux + ((size_t)(b*NFRAME + t + ksh)*NMEL + i));
                }
            }
        }
        As[ak+0][am] = av.x;
        As[ak+1][am] = av.y;
        As[ak+2][am] = av.z;
        As[ak+3][am] = av.w;

        // ---- B tile ---- (all B buffers padded so loads are always in-bounds & zero-padded)
        {
            const int kk  = k0 + bk;
            const int col = n0 + bn;
            float4 bv = *(const float4*)(Bm + (size_t)kk*ldb + col);
            *(float4*)&Bs[bk][bn] = bv;
        }
        __syncthreads();

        #pragma unroll
        for (int k = 0; k < BK; k++) {
            float4 a = *(const float4*)&As[k][ty*4];
            float4 b = *(const float4*)&Bs[k][tx*4];
            acc[0][0] = fmaf(a.x, b.x, acc[0][0]);
            acc[0][1] = fmaf(a.x, b.y, acc[0][1]);
            acc[0][2] = fmaf(a.x, b.z, acc[0][2]);
            acc[0][3] = fmaf(a.x, b.w, acc[0][3]);
            acc[1][0] = fmaf(a.y, b.x, acc[1][0]);
            acc[1][1] = fmaf(a.y, b.y, acc[1][1]);
            acc[1][2] = fmaf(a.y, b.z, acc[1][2]);
            acc[1][3] = fmaf(a.y, b.w, acc[1][3]);
            acc[2][0] = fmaf(a.z, b.x, acc[2][0]);
            acc[2][1] = fmaf(a.z, b.y, acc[2][1]);
            acc[2][2] = fmaf(a.z, b.z, acc[2][2]);
            acc[2][3] = fmaf(a.z, b.w, acc[2][3]);
            acc[3][0] = fmaf(a.w, b.x, acc[3][0]);
            acc[3][1] = fmaf(a.w, b.y, acc[3][1]);
            acc[3][2] = fmaf(a.w, b.z, acc[3][2]);
            acc[3][3] = fmaf(a.w, b.w, acc[3][3]);
        }
        __syncthreads();
    }

    // ---- epilogue ----
    #pragma unroll
    for (int ir = 0; ir < 4; ir++) {
        const int row = m0 + ty*4 + ir;
        if (row >= M) continue;
        #pragma unroll
        for (int jc = 0; jc < 4; jc++) {
            const int col = n0 + tx*4 + jc;
            if (col >= N) continue;
            float v = acc[ir][jc];
            if constexpr (BIAS) v += bias[col];
            C[(size_t)row*ldc + col] = v;
        }
    }
}

// ---------------- LSTM recurrence (persistent over t, batch-partitioned) ----------------
__device__ __forceinline__ float sigm_f(float x){ return 1.f/(1.f + __expf(-x)); }
__device__ __forceinline__ float tanh_f(float x){ float e = __expf(2.f*x); return 1.f - 2.f/(e + 1.f); }

#define LROWS 4
__global__ __launch_bounds__(256)
void lstm_k(const float* __restrict__ X, const float* __restrict__ U, float* __restrict__ H)
{
    __shared__ float hs[LROWS][HID];
    __shared__ float gs[LROWS][GATES];
    const int tid = threadIdx.x;
    const int b0 = blockIdx.x * LROWS;
    const int c0 = tid * 2;

    if (tid < HID) {
        hs[0][tid] = 0.f; hs[1][tid] = 0.f; hs[2][tid] = 0.f; hs[3][tid] = 0.f;
    }
    float cst0 = 0.f, cst1 = 0.f;
    // update-phase ownership
    const int idx0 = c0,   r0u = idx0 >> 7, j0u = idx0 & 127;
    const int idx1 = c0+1, r1u = idx1 >> 7, j1u = idx1 & 127;
    __syncthreads();

    for (int t = 0; t < TSTEPS; t++) {
        float acc0[LROWS], acc1[LROWS];
        #pragma unroll
        for (int r = 0; r < LROWS; r++) {
            const float2 xv = *(const float2*)(X + ((size_t)(b0+r)*TSTEPS + t)*GATES + c0);
            acc0[r] = xv.x; acc1[r] = xv.y;
        }
        for (int k = 0; k < HID; k += 4) {
            float4 hq[LROWS];
            #pragma unroll
            for (int r = 0; r < LROWS; r++) hq[r] = *(const float4*)&hs[r][k];
            #pragma unroll
            for (int j = 0; j < 4; j++) {
                const float2 u = *(const float2*)(U + (size_t)(k+j)*GATES + c0);
                #pragma unroll
                for (int r = 0; r < LROWS; r++) {
                    const float hv = ((const float*)&hq[r])[j];
                    acc0[r] = fmaf(hv, u.x, acc0[r]);
                    acc1[r] = fmaf(hv, u.y, acc1[r]);
                }
            }
        }
        #pragma unroll
        for (int r = 0; r < LROWS; r++) {
            *(float2*)&gs[r][c0] = make_float2(acc0[r], acc1[r]);
        }
        __syncthreads();
        // gate update: thread owns items idx0, idx1
        {
            float gi = gs[r0u][j0u];
            float gf = gs[r0u][128 + j0u];
            float gg = gs[r0u][256 + j0u];
            float go = gs[r0u][384 + j0u];
            float cn = sigm_f(gf)*cst0 + sigm_f(gi)*tanh_f(gg);
            cst0 = cn;
            float hn = sigm_f(go)*tanh_f(cn);
            hs[r0u][j0u] = hn;
            H[((size_t)(b0+r0u)*TSTEPS + t)*HID + j0u] = hn;
        }
        {
            float gi = gs[r1u][j1u];
            float gf = gs[r1u][128 + j1u];
            float gg = gs[r1u][256 + j1u];
            float go = gs[r1u][384 + j1u];
            float cn = sigm_f(gf)*cst1 + sigm_f(gi)*tanh_f(gg);
            cst1 = cn;
            float hn = sigm_f(go)*tanh_f(cn);
            hs[r1u][j1u] = hn;
            H[((size_t)(b0+r1u)*TSTEPS + t)*HID + j1u] = hn;
        }
        __syncthreads();
    }
}

// ---------------- mean over time ----------------
__global__ void mean_k(const float* __restrict__ H, float* __restrict__ Mh){
    const int idx = blockIdx.x*256 + threadIdx.x;
    if (idx >= BATCH*HID) return;
    const int b = idx >> 7, j = idx & 127;
    const float* p = H + (size_t)b*TSTEPS*HID + j;
    float s = 0.f;
    for (int t = 0; t < TSTEPS; t++) s += p[(size_t)t*HID];
    Mh[idx] = s * (1.0f/(float)TSTEPS);
}

// ---------------- launcher ----------------
extern "C" void kernel_launch(void* const* d_in, const int* in_sizes, int n_in,
                              void* d_out, int out_size, void* d_ws, size_t ws_size,
                              hipStream_t stream)
{
    const float* x      = (const float*)d_in[0];
    const float* conv_w = (const float*)d_in[1];
    const float* conv_b = (const float*)d_in[2];
    const float* W1     = (const float*)d_in[3];
    const float* U1     = (const float*)d_in[4];
    const float* b1     = (const float*)d_in[5];
    const float* W2     = (const float*)d_in[6];
    const float* U2     = (const float*)d_in[7];
    const float* b2     = (const float*)d_in[8];
    const float* fc1_w  = (const float*)d_in[9];
    const float* fc1_b  = (const float*)d_in[10];
    const float* proj_w = (const float*)d_in[11];
    const float* proj_b = (const float*)d_in[12];
    float* out = (float*)d_out;

    // ---- workspace layout (must stay under 256 MiB; round-0 failure was a
    //      ~1.25 MB overflow past a 256 MiB d_ws -> GPU memory fault) ----
    char* ws = (char*)d_ws;
    size_t off = 0;
    float* T    = (float*)(ws + off); off = al512(off + (size_t)NFFT*TLD*4);        //  0.72 MB
    float* fb   = (float*)(ws + off); off = al512(off + (size_t)FBROWS*NMEL*4);     //  0.10 MB
    float* Wc   = (float*)(ws + off); off = al512(off + (size_t)384*128*4);         //  0.20 MB
    float* Cw   = (float*)(ws + off); off = al512(off + (size_t)128*64*4);
    float* Cb   = (float*)(ws + off); off = al512(off + (size_t)64*4);
    float* Mh   = (float*)(ws + off); off = al512(off + (size_t)BATCH*HID*4);       //  0.52 MB
    float* MEL  = (float*)(ws + off); off = al512(off + (size_t)BATCH*NFRAME*NMEL*4);   // 42.5 MB
    float* CONV = (float*)(ws + off); off = al512(off + (size_t)BATCH*TSTEPS*NMEL*4);   // 41.4 MB
    float* X    = (float*)(ws + off); off = al512(off + (size_t)BATCH*TSTEPS*GATES*4);  // 165.7 MB
    // Overlays (liveness-disjoint):
    float* DFT = X;     // DFT chunk scratch (18.6 MB) lives only during mel stage; X written after
    float* H1  = MEL;   // MEL dead after CONV computed
    float* H2  = CONV;  // CONV dead after X1 computed
    // Peak footprint: 251,138,560 B = 239.5 MiB < 256 MiB.
    (void)ws_size; (void)out_size; (void)n_in; (void)in_sizes;

    // setup tables
    setup_dft <<<(NFFT*TLD + 255)/256, 256, 0, stream>>>(T);
    setup_fb  <<<(FBROWS*NMEL + 255)/256, 256, 0, stream>>>(fb);
    setup_wc  <<<(384*128 + 255)/256, 256, 0, stream>>>(Wc, conv_w);
    setup_comb<<<(128*64 + 64 + 255)/256, 256, 0, stream>>>(Cw, Cb, fc1_w, fc1_b, proj_w, proj_b);

    // mel spectrogram in chunks: frames @ DFT -> power -> @ fb
    for (int ch = 0; ch < NCHUNK; ch++) {
        const int rowbase = ch * CHROWS;
        gemm_k<A_FRAMES,false><<<dim3(CHROWS/BM, TLD/BN), 256, 0, stream>>>(
            nullptr, T, nullptr, DFT, CHROWS, TLD, NFFT, 0, TLD, TLD, x, rowbase);
        gemm_k<A_POWER,false><<<dim3(CHROWS/BM, NMEL/BN), 256, 0, stream>>>(
            DFT, fb, nullptr, MEL + (size_t)rowbase*NMEL, CHROWS, NMEL, NBIN, TLD, NMEL, NMEL, nullptr, 0);
    }

    // conv1d (k=3, valid) as im2col GEMM, bias fused
    gemm_k<A_CONV3,true><<<dim3(BATCH*TSTEPS/BM, NMEL/BN), 256, 0, stream>>>(
        nullptr, Wc, conv_b, CONV, BATCH*TSTEPS, NMEL, 384, 0, NMEL, NMEL, MEL, 0);

    // layer 1: X1 = CONV @ W1 + b1 ; recurrence
    gemm_k<A_NORMAL,true><<<dim3(BATCH*TSTEPS/BM, GATES/BN), 256, 0, stream>>>(
        CONV, W1, b1, X, BATCH*TSTEPS, GATES, HID, NMEL, GATES, GATES, nullptr, 0);
    lstm_k<<<BATCH/LROWS, 256, 0, stream>>>(X, U1, H1);

    // layer 2
    gemm_k<A_NORMAL,true><<<dim3(BATCH*TSTEPS/BM, GATES/BN), 256, 0, stream>>>(
        H1, W2, b2, X, BATCH*TSTEPS, GATES, HID, HID, GATES, GATES, nullptr, 0);
    lstm_k<<<BATCH/LROWS, 256, 0, stream>>>(X, U2, H2);

    // mean over time, then folded fc1+proj
    mean_k<<<(BATCH*HID + 255)/256, 256, 0, stream>>>(H2, Mh);
    gemm_k<A_NORMAL,true><<<dim3(BATCH/BM, 1), 256, 0, stream>>>(
        Mh, Cw, Cb, out, BATCH, 35, HID, HID, 64, 35, nullptr, 0);
}

// Round 3
// 1747.125 us; speedup vs baseline: 1.2619x; 1.2619x over previous
//
#include <hip/hip_runtime.h>
#include <math.h>

#define PI_D 3.14159265358979323846

// ---------------- dims ----------------
#define BATCH   1024
#define TLEN    16000
#define NFFT    400
#define HOP     200
#define NFRAME  81          // 1 + (16400-400)/200
#define NBIN    201
#define NMEL    128
#define HID     128
#define TSTEPS  79          // after conv k=3 valid
#define GATES   512         // 4*HID

// DFT table layout: [400][448]; cos at cols 0..200, sin at cols 224..424, rest 0
#define TLD     448
#define FBROWS  208         // 201 padded to BK multiple

#define NCHUNK  8
#define CHROWS  (BATCH*NFRAME/NCHUNK)   // 10368

// ---------------- workspace layout ----------------
static inline size_t al512(size_t v){ return (v + 511) & ~((size_t)511); }

// ---------------- setup kernels (double precision) ----------------
__global__ void setup_dft(float* __restrict__ T){
    int idx = blockIdx.x*256 + threadIdx.x;
    if (idx >= NFFT*TLD) return;
    int n = idx / TLD, c = idx % TLD;
    double w = 0.5 - 0.5*cos(2.0*PI_D*(double)n/400.0);   // periodic hann(400)
    double v = 0.0;
    if (c < NBIN) {
        v = w * cos(2.0*PI_D*(double)((n*c)%400)/400.0);
    } else if (c >= 224 && c < 224+NBIN) {
        int k = c - 224;
        v = w * sin(2.0*PI_D*(double)((n*k)%400)/400.0);  // sign irrelevant (squared)
    }
    T[idx] = (float)v;
}

__global__ void setup_fb(float* __restrict__ fb){
    int idx = blockIdx.x*256 + threadIdx.x;
    if (idx >= FBROWS*NMEL) return;
    int f = idx / NMEL, m = idx % NMEL;
    float v = 0.f;
    if (f < NBIN) {
        double melmax = 2595.0 * log10(1.0 + 8000.0/700.0);
        double p0 = 700.0*(pow(10.0, melmax*(double)(m  )/129.0/2595.0) - 1.0);
        double p1 = 700.0*(pow(10.0, melmax*(double)(m+1)/129.0/2595.0) - 1.0);
        double p2 = 700.0*(pow(10.0, melmax*(double)(m+2)/129.0/2595.0) - 1.0);
        double freq = 40.0 * (double)f;   // 8000/200 * f
        double dn = (freq - p0)/(p1 - p0);
        double up = (p2 - freq)/(p2 - p1);
        double t  = dn < up ? dn : up;
        if (t < 0.0) t = 0.0;
        v = (float)t;
    }
    fb[idx] = v;
}

__global__ void setup_wc(float* __restrict__ wc, const float* __restrict__ cw){
    int idx = blockIdx.x*256 + threadIdx.x;
    if (idx >= 384*128) return;
    int kk = idx / 128, o = idx % 128;
    int ksh = kk >> 7, i = kk & 127;
    wc[idx] = cw[o*384 + i*3 + ksh];
}

__global__ void setup_comb(float* __restrict__ cwm, float* __restrict__ cb,
                           const float* __restrict__ fc1w, const float* __restrict__ fc1b,
                           const float* __restrict__ projw, const float* __restrict__ projb){
    int idx = blockIdx.x*256 + threadIdx.x;
    if (idx < 128*64) {
        int i = idx / 64, o = idx % 64;
        float v = 0.f;
        if (o < 35) {
            double s = 0.0;
            for (int m = 0; m < 128; m++) s += (double)fc1w[i*128+m] * (double)projw[m*35+o];
            v = (float)s;
        }
        cwm[idx] = v;
    } else if (idx < 128*64 + 64) {
        int o = idx - 128*64;
        float v = 0.f;
        if (o < 35) {
            double s = (double)projb[o];
            for (int m = 0; m < 128; m++) s += (double)fc1b[m] * (double)projw[m*35+o];
            v = (float)s;
        }
        cb[o] = v;
    }
}

// U (HID x GATES, row-major) -> Ut (GATES x HID): Ut[c][k] = U[k][c]
__global__ void setup_ut(float* __restrict__ ut, const float* __restrict__ u){
    int idx = blockIdx.x*256 + threadIdx.x;
    if (idx >= GATES*HID) return;
    int c = idx >> 7, k = idx & 127;
    ut[idx] = u[(size_t)k*GATES + c];
}

// ---------------- generic tiled GEMM ----------------
#define BM 64
#define BN 64
#define BK 16

enum AMode { A_NORMAL=0, A_FRAMES=1, A_POWER=2, A_CONV3=3 };

template<int AMODE, bool BIAS>
__global__ __launch_bounds__(256)
void gemm_k(const float* __restrict__ A, const float* __restrict__ Bm,
            const float* __restrict__ bias, float* __restrict__ C,
            int M, int N, int K, int lda, int ldb, int ldc,
            const float* __restrict__ aux, int rowbase)
{
    __shared__ float As[BK][BM+4];
    __shared__ float Bs[BK][BN];
    const int tid = threadIdx.x;
    const int tx = tid & 15, ty = tid >> 4;
    const int m0 = blockIdx.x * BM;
    const int n0 = blockIdx.y * BN;

    float acc[4][4] = {{0,0,0,0},{0,0,0,0},{0,0,0,0},{0,0,0,0}};

    const int am = tid >> 2;          // tile row 0..63
    const int ak = (tid & 3) * 4;     // k segment
    const int bk = tid >> 4;          // 0..15
    const int bn = (tid & 15) * 4;

    for (int k0 = 0; k0 < K; k0 += BK) {
        // ---- A tile ----
        float4 av = make_float4(0.f,0.f,0.f,0.f);
        {
            const int row = m0 + am;
            const int kk  = k0 + ak;
            if constexpr (AMODE == A_NORMAL) {
                if (row < M) av = *(const float4*)(A + (size_t)row*lda + kk);
            } else if constexpr (AMODE == A_POWER) {
                if (row < M) {
                    float4 re = *(const float4*)(A + (size_t)row*lda + kk);
                    float4 im = *(const float4*)(A + (size_t)row*lda + 224 + kk);
                    av.x = re.x*re.x + im.x*im.x;
                    av.y = re.y*re.y + im.y*im.y;
                    av.z = re.z*re.z + im.z*im.z;
                    av.w = re.w*re.w + im.w*im.w;
                }
            } else if constexpr (AMODE == A_FRAMES) {
                if (row < M) {
                    const int r = rowbase + row;
                    const int b = r / NFRAME, f = r - b*NFRAME;
                    const float* xb = aux + (size_t)b * TLEN;
                    float tmp[4];
                    #pragma unroll
                    for (int j = 0; j < 4; j++) {
                        int q = f*HOP + (kk + j) - 200;
                        if (q < 0) q = -q;
                        else if (q >= TLEN) q = 2*TLEN - 2 - q;
                        tmp[j] = xb[q];
                    }
                    av = make_float4(tmp[0], tmp[1], tmp[2], tmp[3]);
                }
            } else { // A_CONV3
                if (row < M) {
                    const int r = row;
                    const int b = r / TSTEPS, t = r - b*TSTEPS;
                    const int ksh = kk >> 7, i = kk & 127;
                    av = *(const float4*)(aux + ((size_t)(b*NFRAME + t + ksh)*NMEL + i));
                }
            }
        }
        As[ak+0][am] = av.x;
        As[ak+1][am] = av.y;
        As[ak+2][am] = av.z;
        As[ak+3][am] = av.w;

        // ---- B tile ---- (all B buffers padded so loads are always in-bounds & zero-padded)
        {
            const int kk  = k0 + bk;
            const int col = n0 + bn;
            float4 bv = *(const float4*)(Bm + (size_t)kk*ldb + col);
            *(float4*)&Bs[bk][bn] = bv;
        }
        __syncthreads();

        #pragma unroll
        for (int k = 0; k < BK; k++) {
            float4 a = *(const float4*)&As[k][ty*4];
            float4 b = *(const float4*)&Bs[k][tx*4];
            acc[0][0] = fmaf(a.x, b.x, acc[0][0]);
            acc[0][1] = fmaf(a.x, b.y, acc[0][1]);
            acc[0][2] = fmaf(a.x, b.z, acc[0][2]);
            acc[0][3] = fmaf(a.x, b.w, acc[0][3]);
            acc[1][0] = fmaf(a.y, b.x, acc[1][0]);
            acc[1][1] = fmaf(a.y, b.y, acc[1][1]);
            acc[1][2] = fmaf(a.y, b.z, acc[1][2]);
            acc[1][3] = fmaf(a.y, b.w, acc[1][3]);
            acc[2][0] = fmaf(a.z, b.x, acc[2][0]);
            acc[2][1] = fmaf(a.z, b.y, acc[2][1]);
            acc[2][2] = fmaf(a.z, b.z, acc[2][2]);
            acc[2][3] = fmaf(a.z, b.w, acc[2][3]);
            acc[3][0] = fmaf(a.w, b.x, acc[3][0]);
            acc[3][1] = fmaf(a.w, b.y, acc[3][1]);
            acc[3][2] = fmaf(a.w, b.z, acc[3][2]);
            acc[3][3] = fmaf(a.w, b.w, acc[3][3]);
        }
        __syncthreads();
    }

    // ---- epilogue ----
    #pragma unroll
    for (int ir = 0; ir < 4; ir++) {
        const int row = m0 + ty*4 + ir;
        if (row >= M) continue;
        #pragma unroll
        for (int jc = 0; jc < 4; jc++) {
            const int col = n0 + tx*4 + jc;
            if (col >= N) continue;
            float v = acc[ir][jc];
            if constexpr (BIAS) v += bias[col];
            C[(size_t)row*ldc + col] = v;
        }
    }
}

// ---------------- LSTM recurrence ----------------
// 512 threads = 8 waves (2 waves/SIMD), 256 WGs (1/CU). Each thread owns ONE
// gate column c=tid; its U column (128 floats) lives in registers (statically
// indexed, fully unrolled). Steady-state k-loop: pure FMA + uniform-broadcast
// LDS reads of h. X load issues at loop top, consumed only at loop end.
__device__ __forceinline__ float sigm_f(float x){ return 1.f/(1.f + __expf(-x)); }
__device__ __forceinline__ float tanh_f(float x){ float e = __expf(2.f*x); return 1.f - 2.f/(e + 1.f); }

#define LROWS 4
#define LTHREADS 512
__global__ __launch_bounds__(LTHREADS, 2)
void lstm_k(const float* __restrict__ X, const float* __restrict__ Ut, float* __restrict__ H)
{
    __shared__ float hs[LROWS][HID];     // current hidden state
    __shared__ float gs[LROWS][GATES];   // gate exchange
    const int tid = threadIdx.x;         // 0..511
    const int b0 = blockIdx.x * LROWS;
    const int c  = tid;                  // gate column
    const int ur = tid >> 7, uj = tid & 127;   // (row, h-index) owned in update

    // preload this thread's U column into registers: Ut[c][0..127]
    float4 Ureg[32];
    #pragma unroll
    for (int q = 0; q < 32; q++)
        Ureg[q] = *(const float4*)(Ut + (size_t)c*HID + q*4);

    if (tid < HID) { hs[0][tid]=0.f; hs[1][tid]=0.f; hs[2][tid]=0.f; hs[3][tid]=0.f; }
    float cst = 0.f;
    __syncthreads();

    for (int t = 0; t < TSTEPS; t++) {
        // X for the 4 rows; issued now, consumed after the k-loop (latency hidden)
        float xv[LROWS];
        #pragma unroll
        for (int r = 0; r < LROWS; r++)
            xv[r] = X[((size_t)(b0+r)*TSTEPS + t)*GATES + c];

        float acc[LROWS] = {0.f, 0.f, 0.f, 0.f};
        #pragma unroll
        for (int q = 0; q < 32; q++) {
            const float4 u = Ureg[q];
            #pragma unroll
            for (int r = 0; r < LROWS; r++) {
                const float4 hq = *(const float4*)&hs[r][q*4];   // wave-uniform broadcast
                acc[r] = fmaf(hq.x, u.x, acc[r]);
                acc[r] = fmaf(hq.y, u.y, acc[r]);
                acc[r] = fmaf(hq.z, u.z, acc[r]);
                acc[r] = fmaf(hq.w, u.w, acc[r]);
            }
        }
        #pragma unroll
        for (int r = 0; r < LROWS; r++) gs[r][c] = acc[r] + xv[r];
        __syncthreads();   // gs ready; also: all hs reads for step t are done

        {
            const float gi = gs[ur][uj];
            const float gf = gs[ur][128 + uj];
            const float gg = gs[ur][256 + uj];
            const float go = gs[ur][384 + uj];
            const float cn = sigm_f(gf)*cst + sigm_f(gi)*tanh_f(gg);
            cst = cn;
            const float hn = sigm_f(go)*tanh_f(cn);
            hs[ur][uj] = hn;
            H[((size_t)(b0+ur)*TSTEPS + t)*HID + uj] = hn;
        }
        __syncthreads();   // hs ready for next step; gs safe to overwrite
    }
}

// ---------------- mean over time ----------------
__global__ void mean_k(const float* __restrict__ H, float* __restrict__ Mh){
    const int idx = blockIdx.x*256 + threadIdx.x;
    if (idx >= BATCH*HID) return;
    const int b = idx >> 7, j = idx & 127;
    const float* p = H + (size_t)b*TSTEPS*HID + j;
    float s = 0.f;
    for (int t = 0; t < TSTEPS; t++) s += p[(size_t)t*HID];
    Mh[idx] = s * (1.0f/(float)TSTEPS);
}

// ---------------- launcher ----------------
extern "C" void kernel_launch(void* const* d_in, const int* in_sizes, int n_in,
                              void* d_out, int out_size, void* d_ws, size_t ws_size,
                              hipStream_t stream)
{
    const float* x      = (const float*)d_in[0];
    const float* conv_w = (const float*)d_in[1];
    const float* conv_b = (const float*)d_in[2];
    const float* W1     = (const float*)d_in[3];
    const float* U1     = (const float*)d_in[4];
    const float* b1     = (const float*)d_in[5];
    const float* W2     = (const float*)d_in[6];
    const float* U2     = (const float*)d_in[7];
    const float* b2     = (const float*)d_in[8];
    const float* fc1_w  = (const float*)d_in[9];
    const float* fc1_b  = (const float*)d_in[10];
    const float* proj_w = (const float*)d_in[11];
    const float* proj_b = (const float*)d_in[12];
    float* out = (float*)d_out;

    // ---- workspace layout (stay under 256 MiB) ----
    char* ws = (char*)d_ws;
    size_t off = 0;
    float* T    = (float*)(ws + off); off = al512(off + (size_t)NFFT*TLD*4);        //  0.72 MB
    float* fb   = (float*)(ws + off); off = al512(off + (size_t)FBROWS*NMEL*4);     //  0.10 MB
    float* Wc   = (float*)(ws + off); off = al512(off + (size_t)384*128*4);         //  0.20 MB
    float* Cw   = (float*)(ws + off); off = al512(off + (size_t)128*64*4);
    float* Cb   = (float*)(ws + off); off = al512(off + (size_t)64*4);
    float* Mh   = (float*)(ws + off); off = al512(off + (size_t)BATCH*HID*4);       //  0.52 MB
    float* U1t  = (float*)(ws + off); off = al512(off + (size_t)GATES*HID*4);       //  0.26 MB
    float* U2t  = (float*)(ws + off); off = al512(off + (size_t)GATES*HID*4);       //  0.26 MB
    float* MEL  = (float*)(ws + off); off = al512(off + (size_t)BATCH*NFRAME*NMEL*4);   // 42.5 MB
    float* CONV = (float*)(ws + off); off = al512(off + (size_t)BATCH*TSTEPS*NMEL*4);   // 41.4 MB
    float* X    = (float*)(ws + off); off = al512(off + (size_t)BATCH*TSTEPS*GATES*4);  // 165.7 MB
    // Overlays (liveness-disjoint):
    float* DFT = X;     // DFT chunk scratch (18.6 MB) lives only during mel stage; X written after
    float* H1  = MEL;   // MEL dead after CONV computed
    float* H2  = CONV;  // CONV dead after X1 computed
    // Peak footprint ≈ 240 MiB < 256 MiB.
    (void)ws_size; (void)out_size; (void)n_in; (void)in_sizes;

    // setup tables
    setup_dft <<<(NFFT*TLD + 255)/256, 256, 0, stream>>>(T);
    setup_fb  <<<(FBROWS*NMEL + 255)/256, 256, 0, stream>>>(fb);
    setup_wc  <<<(384*128 + 255)/256, 256, 0, stream>>>(Wc, conv_w);
    setup_comb<<<(128*64 + 64 + 255)/256, 256, 0, stream>>>(Cw, Cb, fc1_w, fc1_b, proj_w, proj_b);
    setup_ut  <<<(GATES*HID + 255)/256, 256, 0, stream>>>(U1t, U1);
    setup_ut  <<<(GATES*HID + 255)/256, 256, 0, stream>>>(U2t, U2);

    // mel spectrogram in chunks: frames @ DFT -> power -> @ fb
    for (int ch = 0; ch < NCHUNK; ch++) {
        const int rowbase = ch * CHROWS;
        gemm_k<A_FRAMES,false><<<dim3(CHROWS/BM, TLD/BN), 256, 0, stream>>>(
            nullptr, T, nullptr, DFT, CHROWS, TLD, NFFT, 0, TLD, TLD, x, rowbase);
        gemm_k<A_POWER,false><<<dim3(CHROWS/BM, NMEL/BN), 256, 0, stream>>>(
            DFT, fb, nullptr, MEL + (size_t)rowbase*NMEL, CHROWS, NMEL, NBIN, TLD, NMEL, NMEL, nullptr, 0);
    }

    // conv1d (k=3, valid) as im2col GEMM, bias fused
    gemm_k<A_CONV3,true><<<dim3(BATCH*TSTEPS/BM, NMEL/BN), 256, 0, stream>>>(
        nullptr, Wc, conv_b, CONV, BATCH*TSTEPS, NMEL, 384, 0, NMEL, NMEL, MEL, 0);

    // layer 1: X1 = CONV @ W1 + b1 ; recurrence
    gemm_k<A_NORMAL,true><<<dim3(BATCH*TSTEPS/BM, GATES/BN), 256, 0, stream>>>(
        CONV, W1, b1, X, BATCH*TSTEPS, GATES, HID, NMEL, GATES, GATES, nullptr, 0);
    lstm_k<<<BATCH/LROWS, LTHREADS, 0, stream>>>(X, U1t, H1);

    // layer 2
    gemm_k<A_NORMAL,true><<<dim3(BATCH*TSTEPS/BM, GATES/BN), 256, 0, stream>>>(
        H1, W2, b2, X, BATCH*TSTEPS, GATES, HID, HID, GATES, GATES, nullptr, 0);
    lstm_k<<<BATCH/LROWS, LTHREADS, 0, stream>>>(X, U2t, H2);

    // mean over time, then folded fc1+proj
    mean_k<<<(BATCH*HID + 255)/256, 256, 0, stream>>>(H2, Mh);
    gemm_k<A_NORMAL,true><<<dim3(BATCH/BM, 1), 256, 0, stream>>>(
        Mh, Cw, Cb, out, BATCH, 35, HID, HID, 64, 35, nullptr, 0);
}

// Round 4
// 1289.475 us; speedup vs baseline: 1.7098x; 1.3549x over previous
//
#include <hip/hip_runtime.h>
#include <math.h>

#define PI_D 3.14159265358979323846

// ---------------- dims ----------------
#define BATCH   1024
#define TLEN    16000
#define NFFT    400
#define HOP     200
#define NFRAME  81          // 1 + (16400-400)/200
#define NBIN    201
#define NMEL    128
#define HID     128
#define TSTEPS  79          // after conv k=3 valid
#define GATES   512         // 4*HID

#define KDFT    416         // 400 padded to 32
#define NDFT    448         // cos 0..200, sin 224..424, rest zero
#define KPOW    224         // 201 padded to 32
#define KCONV   384
#define NCHUNK  8
#define CHROWS  (BATCH*NFRAME/NCHUNK)   // 10368

static inline size_t al512(size_t v){ return (v + 511) & ~((size_t)511); }

// ---------------- bf16 split helpers ----------------
__device__ __forceinline__ unsigned short bf_rne(float f){
    unsigned u = __float_as_uint(f);
    u += 0x7FFF + ((u >> 16) & 1);
    return (unsigned short)(u >> 16);
}
__device__ __forceinline__ void bf_split(float f, unsigned short& h, unsigned short& l){
    h = bf_rne(f);
    float hf = __uint_as_float(((unsigned)h) << 16);
    l = bf_rne(f - hf);
}

typedef short bf16x8 __attribute__((ext_vector_type(8)));
typedef float f32x4  __attribute__((ext_vector_type(4)));
typedef unsigned short us8 __attribute__((ext_vector_type(8)));

// ---------------- setup kernels: B matrices pre-transposed + pre-split ----------------
// Tt[n][k]: DFT table transposed. n<201: cos; 224<=n<425: sin; k>=400: 0.
__global__ void setup_dft_t(unsigned short* __restrict__ th, unsigned short* __restrict__ tl){
    int idx = blockIdx.x*256 + threadIdx.x;
    if (idx >= NDFT*KDFT) return;
    int n = idx / KDFT, k = idx % KDFT;
    double v = 0.0;
    if (k < 400) {
        double w = 0.5 - 0.5*cos(2.0*PI_D*(double)k/400.0);
        if (n < NBIN)                v = w * cos(2.0*PI_D*(double)((k*n)%400)/400.0);
        else if (n >= 224 && n < 425) v = w * sin(2.0*PI_D*(double)((k*(n-224))%400)/400.0);
    }
    unsigned short h, l; bf_split((float)v, h, l);
    th[idx] = h; tl[idx] = l;
}

// fbt[m][f]: mel filterbank transposed; f>=201: 0.
__global__ void setup_fb_t(unsigned short* __restrict__ fh, unsigned short* __restrict__ fl){
    int idx = blockIdx.x*256 + threadIdx.x;
    if (idx >= NMEL*KPOW) return;
    int m = idx / KPOW, f = idx % KPOW;
    float v = 0.f;
    if (f < NBIN) {
        double melmax = 2595.0 * log10(1.0 + 8000.0/700.0);
        double p0 = 700.0*(pow(10.0, melmax*(double)(m  )/129.0/2595.0) - 1.0);
        double p1 = 700.0*(pow(10.0, melmax*(double)(m+1)/129.0/2595.0) - 1.0);
        double p2 = 700.0*(pow(10.0, melmax*(double)(m+2)/129.0/2595.0) - 1.0);
        double freq = 40.0 * (double)f;
        double dn = (freq - p0)/(p1 - p0);
        double up = (p2 - freq)/(p2 - p1);
        double t  = dn < up ? dn : up;
        if (t < 0.0) t = 0.0;
        v = (float)t;
    }
    unsigned short h, l; bf_split(v, h, l);
    fh[idx] = h; fl[idx] = l;
}

// wct[o][kk], kk = ksh*128 + i  ->  conv_w[o][i][ksh]
__global__ void setup_wc_t(unsigned short* __restrict__ wh, unsigned short* __restrict__ wl,
                           const float* __restrict__ cw){
    int idx = blockIdx.x*256 + threadIdx.x;
    if (idx >= NMEL*KCONV) return;
    int o = idx / KCONV, kk = idx % KCONV;
    int ksh = kk >> 7, i = kk & 127;
    unsigned short h, l; bf_split(cw[o*384 + i*3 + ksh], h, l);
    wh[idx] = h; wl[idx] = l;
}

// wt[c][i] = W[i][c]   (W is HID x GATES row-major)
__global__ void setup_w_t(unsigned short* __restrict__ wh, unsigned short* __restrict__ wl,
                          const float* __restrict__ w){
    int idx = blockIdx.x*256 + threadIdx.x;
    if (idx >= GATES*HID) return;
    int c = idx / HID, i = idx % HID;
    unsigned short h, l; bf_split(w[(size_t)i*GATES + c], h, l);
    wh[idx] = h; wl[idx] = l;
}

__global__ void setup_comb(float* __restrict__ cwm, float* __restrict__ cb,
                           const float* __restrict__ fc1w, const float* __restrict__ fc1b,
                           const float* __restrict__ projw, const float* __restrict__ projb){
    int idx = blockIdx.x*256 + threadIdx.x;
    if (idx < 128*64) {
        int i = idx / 64, o = idx % 64;
        float v = 0.f;
        if (o < 35) {
            double s = 0.0;
            for (int m = 0; m < 128; m++) s += (double)fc1w[i*128+m] * (double)projw[m*35+o];
            v = (float)s;
        }
        cwm[idx] = v;
    } else if (idx < 128*64 + 64) {
        int o = idx - 128*64;
        float v = 0.f;
        if (o < 35) {
            double s = (double)projb[o];
            for (int m = 0; m < 128; m++) s += (double)fc1b[m] * (double)projw[m*35+o];
            v = (float)s;
        }
        cb[o] = v;
    }
}

// U (HID x GATES, row-major) -> Ut (GATES x HID)
__global__ void setup_ut(float* __restrict__ ut, const float* __restrict__ u){
    int idx = blockIdx.x*256 + threadIdx.x;
    if (idx >= GATES*HID) return;
    int c = idx >> 7, k = idx & 127;
    ut[idx] = u[(size_t)k*GATES + c];
}

// ---------------- MFMA split-bf16 GEMM ----------------
// 64x64 tile, K-step 32, 256 threads (4 waves). Wave w owns rows w*16..w*16+15.
// A: fp32 source (per AMODE), split hi/lo in staging. B: pre-split BT[n][k].
// 3 MFMA passes: Ah*Bh + Ah*Bl + Al*Bh (lo*lo dropped, ~2^-18 rel).
enum AMode { A_NORMAL=0, A_FRAMES=1, A_POWER=2, A_CONV3=3 };
#define LDK 40   // LDS k-stride (32 + 8 pad), keeps b128 alignment + spreads banks

template<int AMODE, bool BIAS>
__global__ __launch_bounds__(256)
void mgemm_k(const float* __restrict__ A,
             const unsigned short* __restrict__ BTh, const unsigned short* __restrict__ BTl,
             const float* __restrict__ bias, float* __restrict__ C,
             int M, int Ksteps, int lda, int kstride, int ldc,
             const float* __restrict__ aux, int rowbase)
{
    __shared__ unsigned short Ash[64][LDK], Asl[64][LDK];
    __shared__ unsigned short Bsh[64][LDK], Bsl[64][LDK];

    const int tid = threadIdx.x;
    const int m0 = blockIdx.x * 64;
    const int n0 = blockIdx.y * 64;
    const int am = tid >> 2, k8 = (tid & 3) * 8;   // staging ownership

    const int lane = tid & 63, w = tid >> 6;
    const int mrow = (w << 4) + (lane & 15);
    const int koff = (lane >> 4) * 8;

    f32x4 acc[4] = {{0,0,0,0},{0,0,0,0},{0,0,0,0},{0,0,0,0}};

    for (int ks = 0; ks < Ksteps; ks++) {
        const int k0 = ks * 32;
        // ---- stage A (fp32 -> hi/lo) ----
        {
            float v[8];
            const int row = m0 + am;
            const int kk = k0 + k8;
            if constexpr (AMODE == A_NORMAL) {
                *(float4*)&v[0] = *(const float4*)(A + (size_t)row*lda + kk);
                *(float4*)&v[4] = *(const float4*)(A + (size_t)row*lda + kk + 4);
            } else if constexpr (AMODE == A_POWER) {
                float4 re0 = *(const float4*)(A + (size_t)row*lda + kk);
                float4 re1 = *(const float4*)(A + (size_t)row*lda + kk + 4);
                float4 im0 = *(const float4*)(A + (size_t)row*lda + 224 + kk);
                float4 im1 = *(const float4*)(A + (size_t)row*lda + 224 + kk + 4);
                v[0]=re0.x*re0.x+im0.x*im0.x; v[1]=re0.y*re0.y+im0.y*im0.y;
                v[2]=re0.z*re0.z+im0.z*im0.z; v[3]=re0.w*re0.w+im0.w*im0.w;
                v[4]=re1.x*re1.x+im1.x*im1.x; v[5]=re1.y*re1.y+im1.y*im1.y;
                v[6]=re1.z*re1.z+im1.z*im1.z; v[7]=re1.w*re1.w+im1.w*im1.w;
            } else if constexpr (AMODE == A_FRAMES) {
                const int r = rowbase + row;
                const int b = r / NFRAME, f = r - b*NFRAME;
                const float* xb = aux + (size_t)b * TLEN;
                #pragma unroll
                for (int j = 0; j < 8; j++) {
                    int q = f*HOP + (kk + j) - 200;
                    if (q < 0) q = -q;
                    else if (q >= TLEN) q = 2*TLEN - 2 - q;   // k>=400 garbage ok: B rows zero
                    v[j] = xb[q];
                }
            } else { // A_CONV3
                const int r = row;
                const int b = r / TSTEPS, t = r - b*TSTEPS;
                const int ksh = kk >> 7, i = kk & 127;
                const float* src = aux + ((size_t)(b*NFRAME + t + ksh)*NMEL + i);
                *(float4*)&v[0] = *(const float4*)(src);
                *(float4*)&v[4] = *(const float4*)(src + 4);
            }
            us8 hv, lv;
            #pragma unroll
            for (int j = 0; j < 8; j++) {
                unsigned short h, l; bf_split(v[j], h, l);
                hv[j] = h; lv[j] = l;
            }
            *(us8*)&Ash[am][k8] = hv;
            *(us8*)&Asl[am][k8] = lv;
        }
        // ---- stage B (pre-split, pure copy) ----
        {
            const size_t o = (size_t)(n0 + am)*kstride + k0 + k8;
            *(us8*)&Bsh[am][k8] = *(const us8*)(BTh + o);
            *(us8*)&Bsl[am][k8] = *(const us8*)(BTl + o);
        }
        __syncthreads();

        bf16x8 ah = *(const bf16x8*)&Ash[mrow][koff];
        bf16x8 al = *(const bf16x8*)&Asl[mrow][koff];
        #pragma unroll
        for (int nt = 0; nt < 4; nt++) {
            const int nr = (nt << 4) + (lane & 15);
            bf16x8 bh = *(const bf16x8*)&Bsh[nr][koff];
            bf16x8 bl = *(const bf16x8*)&Bsl[nr][koff];
            acc[nt] = __builtin_amdgcn_mfma_f32_16x16x32_bf16(ah, bh, acc[nt], 0, 0, 0);
            acc[nt] = __builtin_amdgcn_mfma_f32_16x16x32_bf16(ah, bl, acc[nt], 0, 0, 0);
            acc[nt] = __builtin_amdgcn_mfma_f32_16x16x32_bf16(al, bh, acc[nt], 0, 0, 0);
        }
        __syncthreads();
    }

    // ---- epilogue: C/D layout col=lane&15, row=quad*4+reg (m89-verified) ----
    const int quad = lane >> 4;
    #pragma unroll
    for (int nt = 0; nt < 4; nt++) {
        const int col = n0 + (nt << 4) + (lane & 15);
        float b = 0.f;
        if constexpr (BIAS) b = bias[col];
        #pragma unroll
        for (int r = 0; r < 4; r++) {
            const int row = m0 + (w << 4) + quad*4 + r;
            C[(size_t)row*ldc + col] = acc[nt][r] + b;
        }
    }
    (void)M;
}

// ---------------- small fp32 GEMM (final 1024x35 only) ----------------
__global__ __launch_bounds__(256)
void gemm_small(const float* __restrict__ A, const float* __restrict__ Bm,
                const float* __restrict__ bias, float* __restrict__ C,
                int M, int N, int K, int lda, int ldb, int ldc)
{
    __shared__ float As[16][64+4];
    __shared__ float Bs[16][64];
    const int tid = threadIdx.x;
    const int tx = tid & 15, ty = tid >> 4;
    const int m0 = blockIdx.x * 64;
    float acc[4][4] = {{0,0,0,0},{0,0,0,0},{0,0,0,0},{0,0,0,0}};
    const int am = tid >> 2, ak = (tid & 3) * 4;
    const int bk = tid >> 4, bn = (tid & 15) * 4;
    for (int k0 = 0; k0 < K; k0 += 16) {
        float4 av = *(const float4*)(A + (size_t)(m0+am)*lda + k0 + ak);
        As[ak+0][am]=av.x; As[ak+1][am]=av.y; As[ak+2][am]=av.z; As[ak+3][am]=av.w;
        *(float4*)&Bs[bk][bn] = *(const float4*)(Bm + (size_t)(k0+bk)*ldb + bn);
        __syncthreads();
        #pragma unroll
        for (int k = 0; k < 16; k++) {
            float4 a = *(const float4*)&As[k][ty*4];
            float4 b = *(const float4*)&Bs[k][tx*4];
            #pragma unroll
            for (int i = 0; i < 4; i++) {
                float av_ = ((const float*)&a)[i];
                acc[i][0] = fmaf(av_, b.x, acc[i][0]);
                acc[i][1] = fmaf(av_, b.y, acc[i][1]);
                acc[i][2] = fmaf(av_, b.z, acc[i][2]);
                acc[i][3] = fmaf(av_, b.w, acc[i][3]);
            }
        }
        __syncthreads();
    }
    #pragma unroll
    for (int ir = 0; ir < 4; ir++) {
        const int row = m0 + ty*4 + ir;
        #pragma unroll
        for (int jc = 0; jc < 4; jc++) {
            const int col = tx*4 + jc;
            if (col < N) C[(size_t)row*ldc + col] = acc[ir][jc] + bias[col];
        }
    }
}

// ---------------- LSTM recurrence ----------------
__device__ __forceinline__ float sigm_f(float x){ return 1.f/(1.f + __expf(-x)); }
__device__ __forceinline__ float tanh_f(float x){ float e = __expf(2.f*x); return 1.f - 2.f/(e + 1.f); }

#define LROWS 4
#define LTHREADS 512
__global__ __launch_bounds__(LTHREADS, 2)
void lstm_k(const float* __restrict__ X, const float* __restrict__ Ut, float* __restrict__ H)
{
    __shared__ float hs[LROWS][HID];
    __shared__ float gs[LROWS][GATES];
    const int tid = threadIdx.x;
    const int b0 = blockIdx.x * LROWS;
    const int c  = tid;
    const int ur = tid >> 7, uj = tid & 127;

    // preload this thread's U column into registers
    float4 Ureg[32];
    #pragma unroll
    for (int q = 0; q < 32; q++)
        Ureg[q] = *(const float4*)(Ut + (size_t)c*HID + q*4);
    // Forbid rematerialization: after this barrier the compiler must assume
    // memory changed, so re-loading Ut later would be unsound -> values stay live.
    asm volatile("" ::: "memory");

    if (tid < HID) { hs[0][tid]=0.f; hs[1][tid]=0.f; hs[2][tid]=0.f; hs[3][tid]=0.f; }
    float cst = 0.f;
    __syncthreads();

    for (int t = 0; t < TSTEPS; t++) {
        float xv[LROWS];
        #pragma unroll
        for (int r = 0; r < LROWS; r++)
            xv[r] = X[((size_t)(b0+r)*TSTEPS + t)*GATES + c];

        float acc[LROWS] = {0.f, 0.f, 0.f, 0.f};
        #pragma unroll
        for (int q = 0; q < 32; q++) {
            const float4 u = Ureg[q];
            #pragma unroll
            for (int r = 0; r < LROWS; r++) {
                const float4 hq = *(const float4*)&hs[r][q*4];
                acc[r] = fmaf(hq.x, u.x, acc[r]);
                acc[r] = fmaf(hq.y, u.y, acc[r]);
                acc[r] = fmaf(hq.z, u.z, acc[r]);
                acc[r] = fmaf(hq.w, u.w, acc[r]);
            }
        }
        #pragma unroll
        for (int r = 0; r < LROWS; r++) gs[r][c] = acc[r] + xv[r];
        __syncthreads();

        {
            const float gi = gs[ur][uj];
            const float gf = gs[ur][128 + uj];
            const float gg = gs[ur][256 + uj];
            const float go = gs[ur][384 + uj];
            const float cn = sigm_f(gf)*cst + sigm_f(gi)*tanh_f(gg);
            cst = cn;
            const float hn = sigm_f(go)*tanh_f(cn);
            hs[ur][uj] = hn;
            H[((size_t)(b0+ur)*TSTEPS + t)*HID + uj] = hn;
        }
        __syncthreads();
    }
}

// ---------------- mean over time ----------------
__global__ void mean_k(const float* __restrict__ H, float* __restrict__ Mh){
    const int idx = blockIdx.x*256 + threadIdx.x;
    if (idx >= BATCH*HID) return;
    const int b = idx >> 7, j = idx & 127;
    const float* p = H + (size_t)b*TSTEPS*HID + j;
    float s = 0.f;
    for (int t = 0; t < TSTEPS; t++) s += p[(size_t)t*HID];
    Mh[idx] = s * (1.0f/(float)TSTEPS);
}

// ---------------- launcher ----------------
extern "C" void kernel_launch(void* const* d_in, const int* in_sizes, int n_in,
                              void* d_out, int out_size, void* d_ws, size_t ws_size,
                              hipStream_t stream)
{
    const float* x      = (const float*)d_in[0];
    const float* conv_w = (const float*)d_in[1];
    const float* conv_b = (const float*)d_in[2];
    const float* W1     = (const float*)d_in[3];
    const float* U1     = (const float*)d_in[4];
    const float* b1     = (const float*)d_in[5];
    const float* W2     = (const float*)d_in[6];
    const float* U2     = (const float*)d_in[7];
    const float* b2     = (const float*)d_in[8];
    const float* fc1_w  = (const float*)d_in[9];
    const float* fc1_b  = (const float*)d_in[10];
    const float* proj_w = (const float*)d_in[11];
    const float* proj_b = (const float*)d_in[12];
    float* out = (float*)d_out;

    // ---- workspace layout (sum = 252,224,000 B = 240.5 MiB < 256 MiB) ----
    char* ws = (char*)d_ws;
    size_t off = 0;
    unsigned short* Tth = (unsigned short*)(ws + off); off = al512(off + (size_t)NDFT*KDFT*2);
    unsigned short* Ttl = (unsigned short*)(ws + off); off = al512(off + (size_t)NDFT*KDFT*2);
    unsigned short* fbh = (unsigned short*)(ws + off); off = al512(off + (size_t)NMEL*KPOW*2);
    unsigned short* fbl = (unsigned short*)(ws + off); off = al512(off + (size_t)NMEL*KPOW*2);
    unsigned short* wch = (unsigned short*)(ws + off); off = al512(off + (size_t)NMEL*KCONV*2);
    unsigned short* wcl = (unsigned short*)(ws + off); off = al512(off + (size_t)NMEL*KCONV*2);
    unsigned short* w1h = (unsigned short*)(ws + off); off = al512(off + (size_t)GATES*HID*2);
    unsigned short* w1l = (unsigned short*)(ws + off); off = al512(off + (size_t)GATES*HID*2);
    unsigned short* w2h = (unsigned short*)(ws + off); off = al512(off + (size_t)GATES*HID*2);
    unsigned short* w2l = (unsigned short*)(ws + off); off = al512(off + (size_t)GATES*HID*2);
    float* Cw   = (float*)(ws + off); off = al512(off + (size_t)128*64*4);
    float* Cb   = (float*)(ws + off); off = al512(off + (size_t)64*4);
    float* Mh   = (float*)(ws + off); off = al512(off + (size_t)BATCH*HID*4);
    float* U1t  = (float*)(ws + off); off = al512(off + (size_t)GATES*HID*4);
    float* U2t  = (float*)(ws + off); off = al512(off + (size_t)GATES*HID*4);
    float* MEL  = (float*)(ws + off); off = al512(off + (size_t)BATCH*NFRAME*NMEL*4);   // 42.5 MB
    float* CONV = (float*)(ws + off); off = al512(off + (size_t)BATCH*TSTEPS*NMEL*4);   // 41.4 MB
    float* X    = (float*)(ws + off); off = al512(off + (size_t)BATCH*TSTEPS*GATES*4);  // 165.7 MB
    float* DFT = X;     // DFT chunk scratch (18.6 MB) dead before X written
    float* H1  = MEL;   // MEL dead after CONV computed
    float* H2  = CONV;  // CONV dead after X1 computed
    (void)ws_size; (void)out_size; (void)n_in; (void)in_sizes;

    // setup tables
    setup_dft_t<<<(NDFT*KDFT + 255)/256, 256, 0, stream>>>(Tth, Ttl);
    setup_fb_t <<<(NMEL*KPOW + 255)/256, 256, 0, stream>>>(fbh, fbl);
    setup_wc_t <<<(NMEL*KCONV + 255)/256, 256, 0, stream>>>(wch, wcl, conv_w);
    setup_w_t  <<<(GATES*HID + 255)/256, 256, 0, stream>>>(w1h, w1l, W1);
    setup_w_t  <<<(GATES*HID + 255)/256, 256, 0, stream>>>(w2h, w2l, W2);
    setup_comb <<<(128*64 + 64 + 255)/256, 256, 0, stream>>>(Cw, Cb, fc1_w, fc1_b, proj_w, proj_b);
    setup_ut   <<<(GATES*HID + 255)/256, 256, 0, stream>>>(U1t, U1);
    setup_ut   <<<(GATES*HID + 255)/256, 256, 0, stream>>>(U2t, U2);

    // mel spectrogram in chunks: frames @ DFT -> power @ fb
    for (int ch = 0; ch < NCHUNK; ch++) {
        const int rowbase = ch * CHROWS;
        mgemm_k<A_FRAMES,false><<<dim3(CHROWS/64, NDFT/64), 256, 0, stream>>>(
            nullptr, Tth, Ttl, nullptr, DFT, CHROWS, KDFT/32, 0, KDFT, NDFT, x, rowbase);
        mgemm_k<A_POWER,false><<<dim3(CHROWS/64, NMEL/64), 256, 0, stream>>>(
            DFT, fbh, fbl, nullptr, MEL + (size_t)rowbase*NMEL, CHROWS, KPOW/32, NDFT, KPOW, NMEL, nullptr, 0);
    }

    // conv1d (k=3, valid) as im2col GEMM, bias fused
    mgemm_k<A_CONV3,true><<<dim3(BATCH*TSTEPS/64, NMEL/64), 256, 0, stream>>>(
        nullptr, wch, wcl, conv_b, CONV, BATCH*TSTEPS, KCONV/32, 0, KCONV, NMEL, MEL, 0);

    // layer 1: X1 = CONV @ W1 + b1 ; recurrence
    mgemm_k<A_NORMAL,true><<<dim3(BATCH*TSTEPS/64, GATES/64), 256, 0, stream>>>(
        CONV, w1h, w1l, b1, X, BATCH*TSTEPS, HID/32, NMEL, HID, GATES, nullptr, 0);
    lstm_k<<<BATCH/LROWS, LTHREADS, 0, stream>>>(X, U1t, H1);

    // layer 2
    mgemm_k<A_NORMAL,true><<<dim3(BATCH*TSTEPS/64, GATES/64), 256, 0, stream>>>(
        H1, w2h, w2l, b2, X, BATCH*TSTEPS, HID/32, HID, HID, GATES, nullptr, 0);
    lstm_k<<<BATCH/LROWS, LTHREADS, 0, stream>>>(X, U2t, H2);

    // mean over time, then folded fc1+proj
    mean_k<<<(BATCH*HID + 255)/256, 256, 0, stream>>>(H2, Mh);
    gemm_small<<<BATCH/64, 256, 0, stream>>>(Mh, Cw, Cb, out, BATCH, 35, HID, HID, 64, 35);
}

// Round 5
// 999.965 us; speedup vs baseline: 2.2049x; 1.2895x over previous
//
#include <hip/hip_runtime.h>
#include <math.h>

#define PI_D 3.14159265358979323846

// ---------------- dims ----------------
#define BATCH   1024
#define TLEN    16000
#define NFFT    400
#define HOP     200
#define NFRAME  81          // 1 + (16400-400)/200
#define NBIN    201
#define NMEL    128
#define HID     128
#define TSTEPS  79          // after conv k=3 valid
#define GATES   512         // 4*HID

#define KDFT    416         // 400 padded to 32
#define NDFT    448         // cos 0..200, sin 224..424, rest zero
#define KPOW    224         // 201 padded to 32
#define KCONV   384
#define NCHUNK  8
#define CHROWS  (BATCH*NFRAME/NCHUNK)   // 10368

static inline size_t al512(size_t v){ return (v + 511) & ~((size_t)511); }

// ---------------- bf16 split helpers ----------------
__device__ __forceinline__ unsigned short bf_rne(float f){
    unsigned u = __float_as_uint(f);
    u += 0x7FFF + ((u >> 16) & 1);
    return (unsigned short)(u >> 16);
}
__device__ __forceinline__ void bf_split(float f, unsigned short& h, unsigned short& l){
    h = bf_rne(f);
    float hf = __uint_as_float(((unsigned)h) << 16);
    l = bf_rne(f - hf);
}

typedef short bf16x8 __attribute__((ext_vector_type(8)));
typedef float f32x4  __attribute__((ext_vector_type(4)));
typedef unsigned short us8 __attribute__((ext_vector_type(8)));
typedef _Float16 f16x8 __attribute__((ext_vector_type(8)));

// ---------------- setup kernels: B matrices pre-transposed + pre-split ----------------
__global__ void setup_dft_t(unsigned short* __restrict__ th, unsigned short* __restrict__ tl){
    int idx = blockIdx.x*256 + threadIdx.x;
    if (idx >= NDFT*KDFT) return;
    int n = idx / KDFT, k = idx % KDFT;
    double v = 0.0;
    if (k < 400) {
        double w = 0.5 - 0.5*cos(2.0*PI_D*(double)k/400.0);
        if (n < NBIN)                v = w * cos(2.0*PI_D*(double)((k*n)%400)/400.0);
        else if (n >= 224 && n < 425) v = w * sin(2.0*PI_D*(double)((k*(n-224))%400)/400.0);
    }
    unsigned short h, l; bf_split((float)v, h, l);
    th[idx] = h; tl[idx] = l;
}

__global__ void setup_fb_t(unsigned short* __restrict__ fh, unsigned short* __restrict__ fl){
    int idx = blockIdx.x*256 + threadIdx.x;
    if (idx >= NMEL*KPOW) return;
    int m = idx / KPOW, f = idx % KPOW;
    float v = 0.f;
    if (f < NBIN) {
        double melmax = 2595.0 * log10(1.0 + 8000.0/700.0);
        double p0 = 700.0*(pow(10.0, melmax*(double)(m  )/129.0/2595.0) - 1.0);
        double p1 = 700.0*(pow(10.0, melmax*(double)(m+1)/129.0/2595.0) - 1.0);
        double p2 = 700.0*(pow(10.0, melmax*(double)(m+2)/129.0/2595.0) - 1.0);
        double freq = 40.0 * (double)f;
        double dn = (freq - p0)/(p1 - p0);
        double up = (p2 - freq)/(p2 - p1);
        double t  = dn < up ? dn : up;
        if (t < 0.0) t = 0.0;
        v = (float)t;
    }
    unsigned short h, l; bf_split(v, h, l);
    fh[idx] = h; fl[idx] = l;
}

__global__ void setup_wc_t(unsigned short* __restrict__ wh, unsigned short* __restrict__ wl,
                           const float* __restrict__ cw){
    int idx = blockIdx.x*256 + threadIdx.x;
    if (idx >= NMEL*KCONV) return;
    int o = idx / KCONV, kk = idx % KCONV;
    int ksh = kk >> 7, i = kk & 127;
    unsigned short h, l; bf_split(cw[o*384 + i*3 + ksh], h, l);
    wh[idx] = h; wl[idx] = l;
}

__global__ void setup_w_t(unsigned short* __restrict__ wh, unsigned short* __restrict__ wl,
                          const float* __restrict__ w){
    int idx = blockIdx.x*256 + threadIdx.x;
    if (idx >= GATES*HID) return;
    int c = idx / HID, i = idx % HID;
    unsigned short h, l; bf_split(w[(size_t)i*GATES + c], h, l);
    wh[idx] = h; wl[idx] = l;
}

__global__ void setup_comb(float* __restrict__ cwm, float* __restrict__ cb,
                           const float* __restrict__ fc1w, const float* __restrict__ fc1b,
                           const float* __restrict__ projw, const float* __restrict__ projb){
    int idx = blockIdx.x*256 + threadIdx.x;
    if (idx < 128*64) {
        int i = idx / 64, o = idx % 64;
        float v = 0.f;
        if (o < 35) {
            double s = 0.0;
            for (int m = 0; m < 128; m++) s += (double)fc1w[i*128+m] * (double)projw[m*35+o];
            v = (float)s;
        }
        cwm[idx] = v;
    } else if (idx < 128*64 + 64) {
        int o = idx - 128*64;
        float v = 0.f;
        if (o < 35) {
            double s = (double)projb[o];
            for (int m = 0; m < 128; m++) s += (double)fc1b[m] * (double)projw[m*35+o];
            v = (float)s;
        }
        cb[o] = v;
    }
}

// U (HID x GATES row-major) -> fp16 in MFMA B-fragment order:
// idx = ((((w*4+ks)*4+nt)*64)+lane)*8 + j ; value = U[k][c],
// k = ks*32 + (lane>>4)*8 + j, c = w*64 + nt*16 + (lane&15).
// This matches the empirically-validated B-frag convention of mgemm_k.
__global__ void setup_uf(_Float16* __restrict__ uf, const float* __restrict__ u){
    int idx = blockIdx.x*256 + threadIdx.x;
    if (idx >= 65536) return;
    int j    = idx & 7;
    int lane = (idx >> 3) & 63;
    int nt   = (idx >> 9) & 3;
    int ks   = (idx >> 11) & 3;
    int w    = (idx >> 13) & 7;
    int k = ks*32 + (lane >> 4)*8 + j;
    int c = w*64 + nt*16 + (lane & 15);
    uf[idx] = (_Float16)u[(size_t)k*GATES + c];
}

// ---------------- MFMA split-bf16 GEMM ----------------
enum AMode { A_NORMAL=0, A_FRAMES=1, A_POWER=2, A_CONV3=3 };
#define LDK 40

template<int AMODE, bool BIAS>
__global__ __launch_bounds__(256)
void mgemm_k(const float* __restrict__ A,
             const unsigned short* __restrict__ BTh, const unsigned short* __restrict__ BTl,
             const float* __restrict__ bias, float* __restrict__ C,
             int M, int Ksteps, int lda, int kstride, int ldc,
             const float* __restrict__ aux, int rowbase)
{
    __shared__ unsigned short Ash[64][LDK], Asl[64][LDK];
    __shared__ unsigned short Bsh[64][LDK], Bsl[64][LDK];

    const int tid = threadIdx.x;
    const int m0 = blockIdx.x * 64;
    const int n0 = blockIdx.y * 64;
    const int am = tid >> 2, k8 = (tid & 3) * 8;

    const int lane = tid & 63, w = tid >> 6;
    const int mrow = (w << 4) + (lane & 15);
    const int koff = (lane >> 4) * 8;

    f32x4 acc[4] = {{0,0,0,0},{0,0,0,0},{0,0,0,0},{0,0,0,0}};

    for (int ks = 0; ks < Ksteps; ks++) {
        const int k0 = ks * 32;
        {
            float v[8];
            const int row = m0 + am;
            const int kk = k0 + k8;
            if constexpr (AMODE == A_NORMAL) {
                *(float4*)&v[0] = *(const float4*)(A + (size_t)row*lda + kk);
                *(float4*)&v[4] = *(const float4*)(A + (size_t)row*lda + kk + 4);
            } else if constexpr (AMODE == A_POWER) {
                float4 re0 = *(const float4*)(A + (size_t)row*lda + kk);
                float4 re1 = *(const float4*)(A + (size_t)row*lda + kk + 4);
                float4 im0 = *(const float4*)(A + (size_t)row*lda + 224 + kk);
                float4 im1 = *(const float4*)(A + (size_t)row*lda + 224 + kk + 4);
                v[0]=re0.x*re0.x+im0.x*im0.x; v[1]=re0.y*re0.y+im0.y*im0.y;
                v[2]=re0.z*re0.z+im0.z*im0.z; v[3]=re0.w*re0.w+im0.w*im0.w;
                v[4]=re1.x*re1.x+im1.x*im1.x; v[5]=re1.y*re1.y+im1.y*im1.y;
                v[6]=re1.z*re1.z+im1.z*im1.z; v[7]=re1.w*re1.w+im1.w*im1.w;
            } else if constexpr (AMODE == A_FRAMES) {
                const int r = rowbase + row;
                const int b = r / NFRAME, f = r - b*NFRAME;
                const float* xb = aux + (size_t)b * TLEN;
                #pragma unroll
                for (int j = 0; j < 8; j++) {
                    int q = f*HOP + (kk + j) - 200;
                    if (q < 0) q = -q;
                    else if (q >= TLEN) q = 2*TLEN - 2 - q;
                    v[j] = xb[q];
                }
            } else { // A_CONV3
                const int r = row;
                const int b = r / TSTEPS, t = r - b*TSTEPS;
                const int ksh = kk >> 7, i = kk & 127;
                const float* src = aux + ((size_t)(b*NFRAME + t + ksh)*NMEL + i);
                *(float4*)&v[0] = *(const float4*)(src);
                *(float4*)&v[4] = *(const float4*)(src + 4);
            }
            us8 hv, lv;
            #pragma unroll
            for (int j = 0; j < 8; j++) {
                unsigned short h, l; bf_split(v[j], h, l);
                hv[j] = h; lv[j] = l;
            }
            *(us8*)&Ash[am][k8] = hv;
            *(us8*)&Asl[am][k8] = lv;
        }
        {
            const size_t o = (size_t)(n0 + am)*kstride + k0 + k8;
            *(us8*)&Bsh[am][k8] = *(const us8*)(BTh + o);
            *(us8*)&Bsl[am][k8] = *(const us8*)(BTl + o);
        }
        __syncthreads();

        bf16x8 ah = *(const bf16x8*)&Ash[mrow][koff];
        bf16x8 al = *(const bf16x8*)&Asl[mrow][koff];
        #pragma unroll
        for (int nt = 0; nt < 4; nt++) {
            const int nr = (nt << 4) + (lane & 15);
            bf16x8 bh = *(const bf16x8*)&Bsh[nr][koff];
            bf16x8 bl = *(const bf16x8*)&Bsl[nr][koff];
            acc[nt] = __builtin_amdgcn_mfma_f32_16x16x32_bf16(ah, bh, acc[nt], 0, 0, 0);
            acc[nt] = __builtin_amdgcn_mfma_f32_16x16x32_bf16(ah, bl, acc[nt], 0, 0, 0);
            acc[nt] = __builtin_amdgcn_mfma_f32_16x16x32_bf16(al, bh, acc[nt], 0, 0, 0);
        }
        __syncthreads();
    }

    const int quad = lane >> 4;
    #pragma unroll
    for (int nt = 0; nt < 4; nt++) {
        const int col = n0 + (nt << 4) + (lane & 15);
        float b = 0.f;
        if constexpr (BIAS) b = bias[col];
        #pragma unroll
        for (int r = 0; r < 4; r++) {
            const int row = m0 + (w << 4) + quad*4 + r;
            C[(size_t)row*ldc + col] = acc[nt][r] + b;
        }
    }
    (void)M;
}

// ---------------- small fp32 GEMM (final 1024x35 only) ----------------
__global__ __launch_bounds__(256)
void gemm_small(const float* __restrict__ A, const float* __restrict__ Bm,
                const float* __restrict__ bias, float* __restrict__ C,
                int M, int N, int K, int lda, int ldb, int ldc)
{
    __shared__ float As[16][64+4];
    __shared__ float Bs[16][64];
    const int tid = threadIdx.x;
    const int tx = tid & 15, ty = tid >> 4;
    const int m0 = blockIdx.x * 64;
    float acc[4][4] = {{0,0,0,0},{0,0,0,0},{0,0,0,0},{0,0,0,0}};
    const int am = tid >> 2, ak = (tid & 3) * 4;
    const int bk = tid >> 4, bn = (tid & 15) * 4;
    for (int k0 = 0; k0 < K; k0 += 16) {
        float4 av = *(const float4*)(A + (size_t)(m0+am)*lda + k0 + ak);
        As[ak+0][am]=av.x; As[ak+1][am]=av.y; As[ak+2][am]=av.z; As[ak+3][am]=av.w;
        *(float4*)&Bs[bk][bn] = *(const float4*)(Bm + (size_t)(k0+bk)*ldb + bn);
        __syncthreads();
        #pragma unroll
        for (int k = 0; k < 16; k++) {
            float4 a = *(const float4*)&As[k][ty*4];
            float4 b = *(const float4*)&Bs[k][tx*4];
            #pragma unroll
            for (int i = 0; i < 4; i++) {
                float av_ = ((const float*)&a)[i];
                acc[i][0] = fmaf(av_, b.x, acc[i][0]);
                acc[i][1] = fmaf(av_, b.y, acc[i][1]);
                acc[i][2] = fmaf(av_, b.z, acc[i][2]);
                acc[i][3] = fmaf(av_, b.w, acc[i][3]);
            }
        }
        __syncthreads();
    }
    #pragma unroll
    for (int ir = 0; ir < 4; ir++) {
        const int row = m0 + ty*4 + ir;
        #pragma unroll
        for (int jc = 0; jc < 4; jc++) {
            const int col = tx*4 + jc;
            if (col < N) C[(size_t)row*ldc + col] = acc[ir][jc] + bias[col];
        }
    }
}

// ---------------- LSTM recurrence: MFMA formulation ----------------
// 256 WGs x 512 threads (8 waves, 2/SIMD). LROWS=4 batch rows per WG inside
// one M=16 MFMA tile (rows 4..15 are zero). Wave w owns gate cols w*64..+63
// (4 N-tiles). U lives in fp16 B-fragments: 16 f16x8 per lane (64 VGPRs),
// preloaded from the fragment-ordered global table; if the compiler
// rematerializes, the fallback is 16 L2-hit b128 loads/step (bounded).
// Gate exchange via LDS with pad-5 stride (conflict-free); h re-enters as
// A-fragments through a padded fp16 LDS tile.
__device__ __forceinline__ float sigm_f(float x){ return 1.f/(1.f + __expf(-x)); }
__device__ __forceinline__ float tanh_f(float x){ float e = __expf(2.f*x); return 1.f - 2.f/(e + 1.f); }

#define LROWS 4
#define LTHREADS 512
#define HPAD 136   // 128 + 8 fp16 pad: keeps 16B alignment, breaks bank aliasing

__global__ __launch_bounds__(LTHREADS, 2)
void lstm_k(const float* __restrict__ X, const _Float16* __restrict__ Uf, float* __restrict__ H)
{
    __shared__ _Float16 hsA[16*HPAD];   // h in A-operand layout; rows 4..15 stay 0
    __shared__ float gs[GATES*5];       // gate exchange [col][row], pad-5
    const int tid = threadIdx.x;
    const int b0 = blockIdx.x * LROWS;
    const int lane = tid & 63, w = tid >> 6;
    const int m16 = lane & 15, quad = lane >> 4;
    const int r = tid >> 7;             // nonlin ownership: batch row 0..3
    const int j = tid & 127;            // nonlin ownership: hidden index

    // preload B fragments (fragment-ordered global table)
    f16x8 bf[4][4];
    #pragma unroll
    for (int ks = 0; ks < 4; ks++)
        #pragma unroll
        for (int nt = 0; nt < 4; nt++)
            bf[ks][nt] = *(const f16x8*)(Uf + ((((w*4 + ks)*4 + nt)*64 + lane) << 3));

    for (int i = tid; i < 16*HPAD; i += LTHREADS) hsA[i] = (_Float16)0.f;
    float cst = 0.f;
    const float* xb = X + ((size_t)(b0 + r)*TSTEPS)*GATES + j;
    __syncthreads();

    for (int t = 0; t < TSTEPS; t++) {
        // early X loads — consumed only after the MFMA + barrier
        const float xi = xb[(size_t)t*GATES];
        const float xf = xb[(size_t)t*GATES + 128];
        const float xg = xb[(size_t)t*GATES + 256];
        const float xo = xb[(size_t)t*GATES + 384];

        // A fragments from LDS (prev step's h)
        f16x8 ah[4];
        #pragma unroll
        for (int ks = 0; ks < 4; ks++)
            ah[ks] = *(const f16x8*)&hsA[m16*HPAD + ks*32 + quad*8];

        f32x4 acc[4] = {{0,0,0,0},{0,0,0,0},{0,0,0,0},{0,0,0,0}};
        #pragma unroll
        for (int ks = 0; ks < 4; ks++)
            #pragma unroll
            for (int nt = 0; nt < 4; nt++)
                acc[nt] = __builtin_amdgcn_mfma_f32_16x16x32_f16(ah[ks], bf[ks][nt], acc[nt], 0, 0, 0);

        // C-layout: col = lane&15 (within N-tile), row = quad*4 + reg.
        // Only quad 0 holds real rows 0..3.
        if (quad == 0) {
            #pragma unroll
            for (int nt = 0; nt < 4; nt++) {
                const int c = w*64 + nt*16 + m16;
                #pragma unroll
                for (int rr = 0; rr < 4; rr++) gs[c*5 + rr] = acc[nt][rr];
            }
        }
        __syncthreads();

        {
            const float gi = gs[(      j)*5 + r] + xi;
            const float gf = gs[(128 + j)*5 + r] + xf;
            const float gg = gs[(256 + j)*5 + r] + xg;
            const float go = gs[(384 + j)*5 + r] + xo;
            const float cn = sigm_f(gf)*cst + sigm_f(gi)*tanh_f(gg);
            cst = cn;
            const float hn = sigm_f(go)*tanh_f(cn);
            H[((size_t)(b0 + r)*TSTEPS + t)*HID + j] = hn;
            hsA[r*HPAD + j] = (_Float16)hn;
        }
        __syncthreads();
    }
}

// ---------------- mean over time ----------------
__global__ void mean_k(const float* __restrict__ H, float* __restrict__ Mh){
    const int idx = blockIdx.x*256 + threadIdx.x;
    if (idx >= BATCH*HID) return;
    const int b = idx >> 7, j = idx & 127;
    const float* p = H + (size_t)b*TSTEPS*HID + j;
    float s = 0.f;
    for (int t = 0; t < TSTEPS; t++) s += p[(size_t)t*HID];
    Mh[idx] = s * (1.0f/(float)TSTEPS);
}

// ---------------- launcher ----------------
extern "C" void kernel_launch(void* const* d_in, const int* in_sizes, int n_in,
                              void* d_out, int out_size, void* d_ws, size_t ws_size,
                              hipStream_t stream)
{
    const float* x      = (const float*)d_in[0];
    const float* conv_w = (const float*)d_in[1];
    const float* conv_b = (const float*)d_in[2];
    const float* W1     = (const float*)d_in[3];
    const float* U1     = (const float*)d_in[4];
    const float* b1     = (const float*)d_in[5];
    const float* W2     = (const float*)d_in[6];
    const float* U2     = (const float*)d_in[7];
    const float* b2     = (const float*)d_in[8];
    const float* fc1_w  = (const float*)d_in[9];
    const float* fc1_b  = (const float*)d_in[10];
    const float* proj_w = (const float*)d_in[11];
    const float* proj_b = (const float*)d_in[12];
    float* out = (float*)d_out;

    // ---- workspace layout (~240 MiB < 256 MiB) ----
    char* ws = (char*)d_ws;
    size_t off = 0;
    unsigned short* Tth = (unsigned short*)(ws + off); off = al512(off + (size_t)NDFT*KDFT*2);
    unsigned short* Ttl = (unsigned short*)(ws + off); off = al512(off + (size_t)NDFT*KDFT*2);
    unsigned short* fbh = (unsigned short*)(ws + off); off = al512(off + (size_t)NMEL*KPOW*2);
    unsigned short* fbl = (unsigned short*)(ws + off); off = al512(off + (size_t)NMEL*KPOW*2);
    unsigned short* wch = (unsigned short*)(ws + off); off = al512(off + (size_t)NMEL*KCONV*2);
    unsigned short* wcl = (unsigned short*)(ws + off); off = al512(off + (size_t)NMEL*KCONV*2);
    unsigned short* w1h = (unsigned short*)(ws + off); off = al512(off + (size_t)GATES*HID*2);
    unsigned short* w1l = (unsigned short*)(ws + off); off = al512(off + (size_t)GATES*HID*2);
    unsigned short* w2h = (unsigned short*)(ws + off); off = al512(off + (size_t)GATES*HID*2);
    unsigned short* w2l = (unsigned short*)(ws + off); off = al512(off + (size_t)GATES*HID*2);
    float* Cw   = (float*)(ws + off); off = al512(off + (size_t)128*64*4);
    float* Cb   = (float*)(ws + off); off = al512(off + (size_t)64*4);
    float* Mh   = (float*)(ws + off); off = al512(off + (size_t)BATCH*HID*4);
    _Float16* Uf1 = (_Float16*)(ws + off); off = al512(off + (size_t)65536*2);
    _Float16* Uf2 = (_Float16*)(ws + off); off = al512(off + (size_t)65536*2);
    float* MEL  = (float*)(ws + off); off = al512(off + (size_t)BATCH*NFRAME*NMEL*4);   // 42.5 MB
    float* CONV = (float*)(ws + off); off = al512(off + (size_t)BATCH*TSTEPS*NMEL*4);   // 41.4 MB
    float* X    = (float*)(ws + off); off = al512(off + (size_t)BATCH*TSTEPS*GATES*4);  // 165.7 MB
    float* DFT = X;     // DFT chunk scratch dead before X written
    float* H1  = MEL;   // MEL dead after CONV computed
    float* H2  = CONV;  // CONV dead after X1 computed
    (void)ws_size; (void)out_size; (void)n_in; (void)in_sizes;

    // setup tables
    setup_dft_t<<<(NDFT*KDFT + 255)/256, 256, 0, stream>>>(Tth, Ttl);
    setup_fb_t <<<(NMEL*KPOW + 255)/256, 256, 0, stream>>>(fbh, fbl);
    setup_wc_t <<<(NMEL*KCONV + 255)/256, 256, 0, stream>>>(wch, wcl, conv_w);
    setup_w_t  <<<(GATES*HID + 255)/256, 256, 0, stream>>>(w1h, w1l, W1);
    setup_w_t  <<<(GATES*HID + 255)/256, 256, 0, stream>>>(w2h, w2l, W2);
    setup_comb <<<(128*64 + 64 + 255)/256, 256, 0, stream>>>(Cw, Cb, fc1_w, fc1_b, proj_w, proj_b);
    setup_uf   <<<65536/256, 256, 0, stream>>>(Uf1, U1);
    setup_uf   <<<65536/256, 256, 0, stream>>>(Uf2, U2);

    // mel spectrogram in chunks: frames @ DFT -> power @ fb
    for (int ch = 0; ch < NCHUNK; ch++) {
        const int rowbase = ch * CHROWS;
        mgemm_k<A_FRAMES,false><<<dim3(CHROWS/64, NDFT/64), 256, 0, stream>>>(
            nullptr, Tth, Ttl, nullptr, DFT, CHROWS, KDFT/32, 0, KDFT, NDFT, x, rowbase);
        mgemm_k<A_POWER,false><<<dim3(CHROWS/64, NMEL/64), 256, 0, stream>>>(
            DFT, fbh, fbl, nullptr, MEL + (size_t)rowbase*NMEL, CHROWS, KPOW/32, NDFT, KPOW, NMEL, nullptr, 0);
    }

    // conv1d (k=3, valid) as im2col GEMM, bias fused
    mgemm_k<A_CONV3,true><<<dim3(BATCH*TSTEPS/64, NMEL/64), 256, 0, stream>>>(
        nullptr, wch, wcl, conv_b, CONV, BATCH*TSTEPS, KCONV/32, 0, KCONV, NMEL, MEL, 0);

    // layer 1: X1 = CONV @ W1 + b1 ; recurrence
    mgemm_k<A_NORMAL,true><<<dim3(BATCH*TSTEPS/64, GATES/64), 256, 0, stream>>>(
        CONV, w1h, w1l, b1, X, BATCH*TSTEPS, HID/32, NMEL, HID, GATES, nullptr, 0);
    lstm_k<<<BATCH/LROWS, LTHREADS, 0, stream>>>(X, Uf1, H1);

    // layer 2
    mgemm_k<A_NORMAL,true><<<dim3(BATCH*TSTEPS/64, GATES/64), 256, 0, stream>>>(
        H1, w2h, w2l, b2, X, BATCH*TSTEPS, HID/32, HID, HID, GATES, nullptr, 0);
    lstm_k<<<BATCH/LROWS, LTHREADS, 0, stream>>>(X, Uf2, H2);

    // mean over time, then folded fc1+proj
    mean_k<<<(BATCH*HID + 255)/256, 256, 0, stream>>>(H2, Mh);
    gemm_small<<<BATCH/64, 256, 0, stream>>>(Mh, Cw, Cb, out, BATCH, 35, HID, HID, 64, 35);
}

// Round 6
// 979.489 us; speedup vs baseline: 2.2509x; 1.0209x over previous
//
#include <hip/hip_runtime.h>
#include <math.h>

#define PI_D 3.14159265358979323846

// ---------------- dims ----------------
#define BATCH   1024
#define TLEN    16000
#define NFFT    400
#define HOP     200
#define NFRAME  81          // 1 + (16400-400)/200
#define NBIN    201
#define NMEL    128
#define HID     128
#define TSTEPS  79          // after conv k=3 valid
#define GATES   512         // 4*HID

#define KDFT    416         // 400 padded to 32
#define NDFT    448         // cos 0..200, sin 224..424, rest zero
#define KPOW    224         // 201 padded to 32
#define KCONV   384
#define NCHUNK  8
#define CHROWS  (BATCH*NFRAME/NCHUNK)   // 10368

static inline size_t al512(size_t v){ return (v + 511) & ~((size_t)511); }

// ---------------- bf16 split helpers ----------------
// RNE split (setup/offline tables)
__device__ __forceinline__ unsigned short bf_rne(float f){
    unsigned u = __float_as_uint(f);
    u += 0x7FFF + ((u >> 16) & 1);
    return (unsigned short)(u >> 16);
}
__device__ __forceinline__ void bf_split(float f, unsigned short& h, unsigned short& l){
    h = bf_rne(f);
    float hf = __uint_as_float(((unsigned)h) << 16);
    l = bf_rne(f - hf);
}
// Fast truncation split (GEMM staging hot path): h=trunc(f), l=trunc(f-h).
// lo captures the hi-truncation remainder exactly to bf16 precision:
// total representation error <= 2^-16 |f| (better than RNE-hi + dropped lo bits).
__device__ __forceinline__ void bf_split_fast(float f, unsigned short& h, unsigned short& l){
    unsigned u = __float_as_uint(f);
    h = (unsigned short)(u >> 16);
    float hf = __uint_as_float(u & 0xFFFF0000u);
    l = (unsigned short)(__float_as_uint(f - hf) >> 16);
}

typedef short bf16x8 __attribute__((ext_vector_type(8)));
typedef float f32x4  __attribute__((ext_vector_type(4)));
typedef unsigned short us8 __attribute__((ext_vector_type(8)));
typedef _Float16 f16x8 __attribute__((ext_vector_type(8)));

// ---------------- setup kernels: B matrices pre-transposed + pre-split ----------------
__global__ void setup_dft_t(unsigned short* __restrict__ th, unsigned short* __restrict__ tl){
    int idx = blockIdx.x*256 + threadIdx.x;
    if (idx >= NDFT*KDFT) return;
    int n = idx / KDFT, k = idx % KDFT;
    double v = 0.0;
    if (k < 400) {
        double w = 0.5 - 0.5*cos(2.0*PI_D*(double)k/400.0);
        if (n < NBIN)                v = w * cos(2.0*PI_D*(double)((k*n)%400)/400.0);
        else if (n >= 224 && n < 425) v = w * sin(2.0*PI_D*(double)((k*(n-224))%400)/400.0);
    }
    unsigned short h, l; bf_split((float)v, h, l);
    th[idx] = h; tl[idx] = l;
}

__global__ void setup_fb_t(unsigned short* __restrict__ fh, unsigned short* __restrict__ fl){
    int idx = blockIdx.x*256 + threadIdx.x;
    if (idx >= NMEL*KPOW) return;
    int m = idx / KPOW, f = idx % KPOW;
    float v = 0.f;
    if (f < NBIN) {
        double melmax = 2595.0 * log10(1.0 + 8000.0/700.0);
        double p0 = 700.0*(pow(10.0, melmax*(double)(m  )/129.0/2595.0) - 1.0);
        double p1 = 700.0*(pow(10.0, melmax*(double)(m+1)/129.0/2595.0) - 1.0);
        double p2 = 700.0*(pow(10.0, melmax*(double)(m+2)/129.0/2595.0) - 1.0);
        double freq = 40.0 * (double)f;
        double dn = (freq - p0)/(p1 - p0);
        double up = (p2 - freq)/(p2 - p1);
        double t  = dn < up ? dn : up;
        if (t < 0.0) t = 0.0;
        v = (float)t;
    }
    unsigned short h, l; bf_split(v, h, l);
    fh[idx] = h; fl[idx] = l;
}

__global__ void setup_wc_t(unsigned short* __restrict__ wh, unsigned short* __restrict__ wl,
                           const float* __restrict__ cw){
    int idx = blockIdx.x*256 + threadIdx.x;
    if (idx >= NMEL*KCONV) return;
    int o = idx / KCONV, kk = idx % KCONV;
    int ksh = kk >> 7, i = kk & 127;
    unsigned short h, l; bf_split(cw[o*384 + i*3 + ksh], h, l);
    wh[idx] = h; wl[idx] = l;
}

__global__ void setup_w_t(unsigned short* __restrict__ wh, unsigned short* __restrict__ wl,
                          const float* __restrict__ w){
    int idx = blockIdx.x*256 + threadIdx.x;
    if (idx >= GATES*HID) return;
    int c = idx / HID, i = idx % HID;
    unsigned short h, l; bf_split(w[(size_t)i*GATES + c], h, l);
    wh[idx] = h; wl[idx] = l;
}

__global__ void setup_comb(float* __restrict__ cwm, float* __restrict__ cb,
                           const float* __restrict__ fc1w, const float* __restrict__ fc1b,
                           const float* __restrict__ projw, const float* __restrict__ projb){
    int idx = blockIdx.x*256 + threadIdx.x;
    if (idx < 128*64) {
        int i = idx / 64, o = idx % 64;
        float v = 0.f;
        if (o < 35) {
            double s = 0.0;
            for (int m = 0; m < 128; m++) s += (double)fc1w[i*128+m] * (double)projw[m*35+o];
            v = (float)s;
        }
        cwm[idx] = v;
    } else if (idx < 128*64 + 64) {
        int o = idx - 128*64;
        float v = 0.f;
        if (o < 35) {
            double s = (double)projb[o];
            for (int m = 0; m < 128; m++) s += (double)fc1b[m] * (double)projw[m*35+o];
            v = (float)s;
        }
        cb[o] = v;
    }
}

// U (HID x GATES row-major) -> fp16 in MFMA B-fragment order.
__global__ void setup_uf(_Float16* __restrict__ uf, const float* __restrict__ u){
    int idx = blockIdx.x*256 + threadIdx.x;
    if (idx >= 65536) return;
    int j    = idx & 7;
    int lane = (idx >> 3) & 63;
    int nt   = (idx >> 9) & 3;
    int ks   = (idx >> 11) & 3;
    int w    = (idx >> 13) & 7;
    int k = ks*32 + (lane >> 4)*8 + j;
    int c = w*64 + nt*16 + (lane & 15);
    uf[idx] = (_Float16)u[(size_t)k*GATES + c];
}

// ---------------- MFMA split-bf16 GEMM ----------------
enum AMode { A_NORMAL=0, A_FRAMES=1, A_POWER=2, A_CONV3=3 };
#define LDK 40

template<int AMODE, bool BIAS>
__global__ __launch_bounds__(256)
void mgemm_k(const float* __restrict__ A,
             const unsigned short* __restrict__ BTh, const unsigned short* __restrict__ BTl,
             const float* __restrict__ bias, float* __restrict__ C,
             int M, int Ksteps, int lda, int kstride, int ldc,
             const float* __restrict__ aux, int rowbase)
{
    __shared__ unsigned short Ash[64][LDK], Asl[64][LDK];
    __shared__ unsigned short Bsh[64][LDK], Bsl[64][LDK];

    const int tid = threadIdx.x;
    const int m0 = blockIdx.x * 64;
    const int n0 = blockIdx.y * 64;
    const int am = tid >> 2, k8 = (tid & 3) * 8;

    const int lane = tid & 63, w = tid >> 6;
    const int mrow = (w << 4) + (lane & 15);
    const int koff = (lane >> 4) * 8;

    f32x4 acc[4] = {{0,0,0,0},{0,0,0,0},{0,0,0,0},{0,0,0,0}};

    for (int ks = 0; ks < Ksteps; ks++) {
        const int k0 = ks * 32;
        {
            float v[8];
            const int row = m0 + am;
            const int kk = k0 + k8;
            if constexpr (AMODE == A_NORMAL) {
                *(float4*)&v[0] = *(const float4*)(A + (size_t)row*lda + kk);
                *(float4*)&v[4] = *(const float4*)(A + (size_t)row*lda + kk + 4);
            } else if constexpr (AMODE == A_POWER) {
                float4 re0 = *(const float4*)(A + (size_t)row*lda + kk);
                float4 re1 = *(const float4*)(A + (size_t)row*lda + kk + 4);
                float4 im0 = *(const float4*)(A + (size_t)row*lda + 224 + kk);
                float4 im1 = *(const float4*)(A + (size_t)row*lda + 224 + kk + 4);
                v[0]=re0.x*re0.x+im0.x*im0.x; v[1]=re0.y*re0.y+im0.y*im0.y;
                v[2]=re0.z*re0.z+im0.z*im0.z; v[3]=re0.w*re0.w+im0.w*im0.w;
                v[4]=re1.x*re1.x+im1.x*im1.x; v[5]=re1.y*re1.y+im1.y*im1.y;
                v[6]=re1.z*re1.z+im1.z*im1.z; v[7]=re1.w*re1.w+im1.w*im1.w;
            } else if constexpr (AMODE == A_FRAMES) {
                const int r = rowbase + row;
                const int b = r / NFRAME, f = r - b*NFRAME;
                const float* xb = aux + (size_t)b * TLEN;
                #pragma unroll
                for (int j = 0; j < 8; j++) {
                    int q = f*HOP + (kk + j) - 200;
                    if (q < 0) q = -q;
                    else if (q >= TLEN) q = 2*TLEN - 2 - q;
                    v[j] = xb[q];
                }
            } else { // A_CONV3
                const int r = row;
                const int b = r / TSTEPS, t = r - b*TSTEPS;
                const int ksh = kk >> 7, i = kk & 127;
                const float* src = aux + ((size_t)(b*NFRAME + t + ksh)*NMEL + i);
                *(float4*)&v[0] = *(const float4*)(src);
                *(float4*)&v[4] = *(const float4*)(src + 4);
            }
            us8 hv, lv;
            #pragma unroll
            for (int j = 0; j < 8; j++) {
                unsigned short h, l; bf_split_fast(v[j], h, l);
                hv[j] = h; lv[j] = l;
            }
            *(us8*)&Ash[am][k8] = hv;
            *(us8*)&Asl[am][k8] = lv;
        }
        {
            const size_t o = (size_t)(n0 + am)*kstride + k0 + k8;
            *(us8*)&Bsh[am][k8] = *(const us8*)(BTh + o);
            *(us8*)&Bsl[am][k8] = *(const us8*)(BTl + o);
        }
        __syncthreads();

        bf16x8 ah = *(const bf16x8*)&Ash[mrow][koff];
        bf16x8 al = *(const bf16x8*)&Asl[mrow][koff];
        #pragma unroll
        for (int nt = 0; nt < 4; nt++) {
            const int nr = (nt << 4) + (lane & 15);
            bf16x8 bh = *(const bf16x8*)&Bsh[nr][koff];
            bf16x8 bl = *(const bf16x8*)&Bsl[nr][koff];
            acc[nt] = __builtin_amdgcn_mfma_f32_16x16x32_bf16(ah, bh, acc[nt], 0, 0, 0);
            acc[nt] = __builtin_amdgcn_mfma_f32_16x16x32_bf16(ah, bl, acc[nt], 0, 0, 0);
            acc[nt] = __builtin_amdgcn_mfma_f32_16x16x32_bf16(al, bh, acc[nt], 0, 0, 0);
        }
        __syncthreads();
    }

    const int quad = lane >> 4;
    #pragma unroll
    for (int nt = 0; nt < 4; nt++) {
        const int col = n0 + (nt << 4) + (lane & 15);
        float b = 0.f;
        if constexpr (BIAS) b = bias[col];
        #pragma unroll
        for (int r = 0; r < 4; r++) {
            const int row = m0 + (w << 4) + quad*4 + r;
            C[(size_t)row*ldc + col] = acc[nt][r] + b;
        }
    }
    (void)M;
}

// ---------------- small fp32 GEMM (final 1024x35 only) ----------------
__global__ __launch_bounds__(256)
void gemm_small(const float* __restrict__ A, const float* __restrict__ Bm,
                const float* __restrict__ bias, float* __restrict__ C,
                int M, int N, int K, int lda, int ldb, int ldc)
{
    __shared__ float As[16][64+4];
    __shared__ float Bs[16][64];
    const int tid = threadIdx.x;
    const int tx = tid & 15, ty = tid >> 4;
    const int m0 = blockIdx.x * 64;
    float acc[4][4] = {{0,0,0,0},{0,0,0,0},{0,0,0,0},{0,0,0,0}};
    const int am = tid >> 2, ak = (tid & 3) * 4;
    const int bk = tid >> 4, bn = (tid & 15) * 4;
    for (int k0 = 0; k0 < K; k0 += 16) {
        float4 av = *(const float4*)(A + (size_t)(m0+am)*lda + k0 + ak);
        As[ak+0][am]=av.x; As[ak+1][am]=av.y; As[ak+2][am]=av.z; As[ak+3][am]=av.w;
        *(float4*)&Bs[bk][bn] = *(const float4*)(Bm + (size_t)(k0+bk)*ldb + bn);
        __syncthreads();
        #pragma unroll
        for (int k = 0; k < 16; k++) {
            float4 a = *(const float4*)&As[k][ty*4];
            float4 b = *(const float4*)&Bs[k][tx*4];
            #pragma unroll
            for (int i = 0; i < 4; i++) {
                float av_ = ((const float*)&a)[i];
                acc[i][0] = fmaf(av_, b.x, acc[i][0]);
                acc[i][1] = fmaf(av_, b.y, acc[i][1]);
                acc[i][2] = fmaf(av_, b.z, acc[i][2]);
                acc[i][3] = fmaf(av_, b.w, acc[i][3]);
            }
        }
        __syncthreads();
    }
    #pragma unroll
    for (int ir = 0; ir < 4; ir++) {
        const int row = m0 + ty*4 + ir;
        #pragma unroll
        for (int jc = 0; jc < 4; jc++) {
            const int col = tx*4 + jc;
            if (col < N) C[(size_t)row*ldc + col] = acc[ir][jc] + bias[col];
        }
    }
}

// ---------------- LSTM recurrence: MFMA, U forced register-resident ----------------
__device__ __forceinline__ float sigm_f(float x){ return 1.f/(1.f + __expf(-x)); }
__device__ __forceinline__ float tanh_f(float x){ float e = __expf(2.f*x); return 1.f - 2.f/(e + 1.f); }

#define LROWS 4
#define LTHREADS 512
#define HPAD 136

__global__ __launch_bounds__(LTHREADS, 2)
void lstm_k(const float* __restrict__ X, const _Float16* __restrict__ Uf, float* __restrict__ H)
{
    __shared__ _Float16 hsA[16*HPAD];
    __shared__ float gs[GATES*5];
    const int tid = threadIdx.x;
    const int b0 = blockIdx.x * LROWS;
    const int lane = tid & 63, w = tid >> 6;
    const int m16 = lane & 15, quad = lane >> 4;
    const int r = tid >> 7;
    const int j = tid & 127;

    // Preload B fragments, then pin them in VGPRs with a volatile asm
    // REDEFINITION — rematerialization cannot clone past it (R4/R5 lesson:
    // plain loads get re-issued from L2 every step -> 25 TB/s L2-bound).
    f32x4 bfr[4][4];
    #pragma unroll
    for (int ks = 0; ks < 4; ks++)
        #pragma unroll
        for (int nt = 0; nt < 4; nt++) {
            bfr[ks][nt] = *(const f32x4*)(Uf + ((((w*4 + ks)*4 + nt)*64 + lane) << 3));
            asm volatile("" : "+v"(bfr[ks][nt]));
        }

    for (int i = tid; i < 16*HPAD; i += LTHREADS) hsA[i] = (_Float16)0.f;
    float cst = 0.f;
    const float* xb = X + ((size_t)(b0 + r)*TSTEPS)*GATES + j;
    __syncthreads();

    // X prefetch: values for step t loaded one iteration early
    float xi = xb[0], xf = xb[128], xg = xb[256], xo = xb[384];

    for (int t = 0; t < TSTEPS; t++) {
        float xi_n = 0.f, xf_n = 0.f, xg_n = 0.f, xo_n = 0.f;
        if (t + 1 < TSTEPS) {
            const float* xp = xb + (size_t)(t + 1)*GATES;
            xi_n = xp[0]; xf_n = xp[128]; xg_n = xp[256]; xo_n = xp[384];
        }

        f16x8 ah[4];
        #pragma unroll
        for (int ks = 0; ks < 4; ks++)
            ah[ks] = *(const f16x8*)&hsA[m16*HPAD + ks*32 + quad*8];

        f32x4 acc[4] = {{0,0,0,0},{0,0,0,0},{0,0,0,0},{0,0,0,0}};
        #pragma unroll
        for (int ks = 0; ks < 4; ks++)
            #pragma unroll
            for (int nt = 0; nt < 4; nt++)
                acc[nt] = __builtin_amdgcn_mfma_f32_16x16x32_f16(
                    ah[ks], __builtin_bit_cast(f16x8, bfr[ks][nt]), acc[nt], 0, 0, 0);

        if (quad == 0) {
            #pragma unroll
            for (int nt = 0; nt < 4; nt++) {
                const int c = w*64 + nt*16 + m16;
                #pragma unroll
                for (int rr = 0; rr < 4; rr++) gs[c*5 + rr] = acc[nt][rr];
            }
        }
        __syncthreads();

        {
            const float gi = gs[(      j)*5 + r] + xi;
            const float gf = gs[(128 + j)*5 + r] + xf;
            const float gg = gs[(256 + j)*5 + r] + xg;
            const float go = gs[(384 + j)*5 + r] + xo;
            const float cn = sigm_f(gf)*cst + sigm_f(gi)*tanh_f(gg);
            cst = cn;
            const float hn = sigm_f(go)*tanh_f(cn);
            H[((size_t)(b0 + r)*TSTEPS + t)*HID + j] = hn;
            hsA[r*HPAD + j] = (_Float16)hn;
        }
        __syncthreads();

        xi = xi_n; xf = xf_n; xg = xg_n; xo = xo_n;
    }
}

// ---------------- mean over time ----------------
__global__ void mean_k(const float* __restrict__ H, float* __restrict__ Mh){
    const int idx = blockIdx.x*256 + threadIdx.x;
    if (idx >= BATCH*HID) return;
    const int b = idx >> 7, j = idx & 127;
    const float* p = H + (size_t)b*TSTEPS*HID + j;
    float s = 0.f;
    for (int t = 0; t < TSTEPS; t++) s += p[(size_t)t*HID];
    Mh[idx] = s * (1.0f/(float)TSTEPS);
}

// ---------------- launcher ----------------
extern "C" void kernel_launch(void* const* d_in, const int* in_sizes, int n_in,
                              void* d_out, int out_size, void* d_ws, size_t ws_size,
                              hipStream_t stream)
{
    const float* x      = (const float*)d_in[0];
    const float* conv_w = (const float*)d_in[1];
    const float* conv_b = (const float*)d_in[2];
    const float* W1     = (const float*)d_in[3];
    const float* U1     = (const float*)d_in[4];
    const float* b1     = (const float*)d_in[5];
    const float* W2     = (const float*)d_in[6];
    const float* U2     = (const float*)d_in[7];
    const float* b2     = (const float*)d_in[8];
    const float* fc1_w  = (const float*)d_in[9];
    const float* fc1_b  = (const float*)d_in[10];
    const float* proj_w = (const float*)d_in[11];
    const float* proj_b = (const float*)d_in[12];
    float* out = (float*)d_out;

    // ---- workspace layout (~240 MiB < 256 MiB) ----
    char* ws = (char*)d_ws;
    size_t off = 0;
    unsigned short* Tth = (unsigned short*)(ws + off); off = al512(off + (size_t)NDFT*KDFT*2);
    unsigned short* Ttl = (unsigned short*)(ws + off); off = al512(off + (size_t)NDFT*KDFT*2);
    unsigned short* fbh = (unsigned short*)(ws + off); off = al512(off + (size_t)NMEL*KPOW*2);
    unsigned short* fbl = (unsigned short*)(ws + off); off = al512(off + (size_t)NMEL*KPOW*2);
    unsigned short* wch = (unsigned short*)(ws + off); off = al512(off + (size_t)NMEL*KCONV*2);
    unsigned short* wcl = (unsigned short*)(ws + off); off = al512(off + (size_t)NMEL*KCONV*2);
    unsigned short* w1h = (unsigned short*)(ws + off); off = al512(off + (size_t)GATES*HID*2);
    unsigned short* w1l = (unsigned short*)(ws + off); off = al512(off + (size_t)GATES*HID*2);
    unsigned short* w2h = (unsigned short*)(ws + off); off = al512(off + (size_t)GATES*HID*2);
    unsigned short* w2l = (unsigned short*)(ws + off); off = al512(off + (size_t)GATES*HID*2);
    float* Cw   = (float*)(ws + off); off = al512(off + (size_t)128*64*4);
    float* Cb   = (float*)(ws + off); off = al512(off + (size_t)64*4);
    float* Mh   = (float*)(ws + off); off = al512(off + (size_t)BATCH*HID*4);
    _Float16* Uf1 = (_Float16*)(ws + off); off = al512(off + (size_t)65536*2);
    _Float16* Uf2 = (_Float16*)(ws + off); off = al512(off + (size_t)65536*2);
    float* MEL  = (float*)(ws + off); off = al512(off + (size_t)BATCH*NFRAME*NMEL*4);   // 42.5 MB
    float* CONV = (float*)(ws + off); off = al512(off + (size_t)BATCH*TSTEPS*NMEL*4);   // 41.4 MB
    float* X    = (float*)(ws + off); off = al512(off + (size_t)BATCH*TSTEPS*GATES*4);  // 165.7 MB
    float* DFT = X;     // DFT chunk scratch dead before X written
    float* H1  = MEL;   // MEL dead after CONV computed
    float* H2  = CONV;  // CONV dead after X1 computed
    (void)ws_size; (void)out_size; (void)n_in; (void)in_sizes;

    // setup tables
    setup_dft_t<<<(NDFT*KDFT + 255)/256, 256, 0, stream>>>(Tth, Ttl);
    setup_fb_t <<<(NMEL*KPOW + 255)/256, 256, 0, stream>>>(fbh, fbl);
    setup_wc_t <<<(NMEL*KCONV + 255)/256, 256, 0, stream>>>(wch, wcl, conv_w);
    setup_w_t  <<<(GATES*HID + 255)/256, 256, 0, stream>>>(w1h, w1l, W1);
    setup_w_t  <<<(GATES*HID + 255)/256, 256, 0, stream>>>(w2h, w2l, W2);
    setup_comb <<<(128*64 + 64 + 255)/256, 256, 0, stream>>>(Cw, Cb, fc1_w, fc1_b, proj_w, proj_b);
    setup_uf   <<<65536/256, 256, 0, stream>>>(Uf1, U1);
    setup_uf   <<<65536/256, 256, 0, stream>>>(Uf2, U2);

    // mel spectrogram in chunks: frames @ DFT -> power @ fb
    for (int ch = 0; ch < NCHUNK; ch++) {
        const int rowbase = ch * CHROWS;
        mgemm_k<A_FRAMES,false><<<dim3(CHROWS/64, NDFT/64), 256, 0, stream>>>(
            nullptr, Tth, Ttl, nullptr, DFT, CHROWS, KDFT/32, 0, KDFT, NDFT, x, rowbase);
        mgemm_k<A_POWER,false><<<dim3(CHROWS/64, NMEL/64), 256, 0, stream>>>(
            DFT, fbh, fbl, nullptr, MEL + (size_t)rowbase*NMEL, CHROWS, KPOW/32, NDFT, KPOW, NMEL, nullptr, 0);
    }

    // conv1d (k=3, valid) as im2col GEMM, bias fused
    mgemm_k<A_CONV3,true><<<dim3(BATCH*TSTEPS/64, NMEL/64), 256, 0, stream>>>(
        nullptr, wch, wcl, conv_b, CONV, BATCH*TSTEPS, KCONV/32, 0, KCONV, NMEL, MEL, 0);

    // layer 1: X1 = CONV @ W1 + b1 ; recurrence
    mgemm_k<A_NORMAL,true><<<dim3(BATCH*TSTEPS/64, GATES/64), 256, 0, stream>>>(
        CONV, w1h, w1l, b1, X, BATCH*TSTEPS, HID/32, NMEL, HID, GATES, nullptr, 0);
    lstm_k<<<BATCH/LROWS, LTHREADS, 0, stream>>>(X, Uf1, H1);

    // layer 2
    mgemm_k<A_NORMAL,true><<<dim3(BATCH*TSTEPS/64, GATES/64), 256, 0, stream>>>(
        H1, w2h, w2l, b2, X, BATCH*TSTEPS, HID/32, HID, HID, GATES, nullptr, 0);
    lstm_k<<<BATCH/LROWS, LTHREADS, 0, stream>>>(X, Uf2, H2);

    // mean over time, then folded fc1+proj
    mean_k<<<(BATCH*HID + 255)/256, 256, 0, stream>>>(H2, Mh);
    gemm_small<<<BATCH/64, 256, 0, stream>>>(Mh, Cw, Cb, out, BATCH, 35, HID, HID, 64, 35);
}